// Round 5
// baseline (702.316 us; speedup 1.0000x reference)
//
#include <hip/hip_runtime.h>

#define N_NODES 100000
#define E_HALF  500000
#define E_TOT   1000000
#define NFEAT   128
#define NHID    64
#define NCLS    40
#define SCAN_T  1024
#define SCAN_NB 98   // ceil(N_NODES/1024)

// rev is arithmetic by construction: rev = concat(arange+E_HALF, arange)
__device__ __forceinline__ int REV(int e) { return (e < E_HALF) ? e + E_HALF : e - E_HALF; }

// ---------------- node norms (pass-1 only; pass-2 norm fused into agg1) ----------------
template<int D>
__global__ __launch_bounds__(256) void row_norm_k(const float* __restrict__ x, float* __restrict__ nrm) {
    int w = (blockIdx.x * 256 + threadIdx.x) >> 6;
    int lane = threadIdx.x & 63;
    if (w >= N_NODES) return;
    const float* row = x + (size_t)w * D;
    float s = 0.f;
#pragma unroll
    for (int i = 0; i < D / 64; ++i) { float v = row[lane + 64 * i]; s = fmaf(v, v, s); }
#pragma unroll
    for (int off = 32; off; off >>= 1) s += __shfl_xor(s, off);
    if (lane == 0) nrm[w] = sqrtf(s);
}

// ---------------- cosine sim on edge pairs (16 lanes / undirected pair), no atomics ----------------
template<int D, bool MASKED>
__global__ __launch_bounds__(256) void sim_k(const float* __restrict__ f, const float* __restrict__ nrm,
                                             const int* __restrict__ src, const int* __restrict__ dst,
                                             const float* __restrict__ we_mask,
                                             float* __restrict__ sim) {
    int g = blockIdx.x * 256 + threadIdx.x;
    int ep = g >> 4, sl = g & 15;
    if (ep >= E_HALF) return;
    bool m0 = true, m1 = true;
    if (MASKED) {
        m0 = we_mask[ep] > 0.f;
        m1 = we_mask[ep + E_HALF] > 0.f;
        if (!m0 && !m1) {               // both directions dropped in pass 1: skip the row gathers
            if (sl == 0) { sim[ep] = 0.f; sim[ep + E_HALF] = 0.f; }
            return;
        }
    }
    int s = src[ep], d = dst[ep];
    const float* fa = f + (size_t)s * D + sl * (D / 16);
    const float* fb = f + (size_t)d * D + sl * (D / 16);
    float acc = 0.f;
#pragma unroll
    for (int i = 0; i < D / 16; i += 4) {
        float4 va = *(const float4*)(fa + i);
        float4 vb = *(const float4*)(fb + i);
        acc = fmaf(va.x, vb.x, acc); acc = fmaf(va.y, vb.y, acc);
        acc = fmaf(va.z, vb.z, acc); acc = fmaf(va.w, vb.w, acc);
    }
    acc += __shfl_xor(acc, 8); acc += __shfl_xor(acc, 4);
    acc += __shfl_xor(acc, 2); acc += __shfl_xor(acc, 1);
    if (sl == 0) {
        float na = nrm[s]; na = (na == 0.f) ? 1.f : na;
        float nb = nrm[d]; nb = (nb == 0.f) ? 1.f : nb;
        float c = acc / (na * nb);
        float t = (c < 0.1f) ? 0.f : c;      // t >= 0 always
        sim[ep]          = m0 ? t : 0.f;
        sim[ep + E_HALF] = m1 ? t : 0.f;
    }
}

// ---------------- rowsum[j] = sum of sim over out-edges (CSR row j), 4 lanes/node ----------------
__global__ __launch_bounds__(256) void rowsum_k(const float* __restrict__ sim, const int* __restrict__ row_start,
                                                const int2* __restrict__ csr, float* __restrict__ rowsum) {
    int g = blockIdx.x * 256 + threadIdx.x;
    int j = g >> 2, l = g & 3;
    if (j >= N_NODES) return;
    int e0 = row_start[j], e1 = row_start[j + 1];
    float s = 0.f;
    for (int t = e0 + l; t < e1; t += 4) s += sim[csr[t].y];
    s += __shfl_xor(s, 1); s += __shfl_xor(s, 2);
    if (l == 0) rowsum[j] = s;
}

// ---------------- fused L1-normalize + learnable keep/drop -> w_e (pure streaming) ----------------
__global__ __launch_bounds__(256) void keep_k(const float* __restrict__ sim,
                                              const int* __restrict__ src, const int* __restrict__ dst,
                                              const float* __restrict__ rowsum,
                                              const float* __restrict__ Wd, const float* __restrict__ bd,
                                              float* __restrict__ we) {
    int e = blockIdx.x * 256 + threadIdx.x;
    if (e >= E_TOT) return;
    int s = src[e], d = dst[e];
    float rs = rowsum[s]; rs = (rs == 0.f) ? 1.f : rs;
    float rd = rowsum[d]; rd = (rd == 0.f) ? 1.f : rd;      // src[rev[e]] == dst[e]
    float ae = sim[e] / rs;
    float ar = sim[REV(e)] / rd;
    float z = ae * Wd[0] + ar * Wd[1] + bd[0];
    float av = (z > 0.f) ? ae : 0.f;          // sigmoid(z)>0.5 <=> z>0
    we[e] = (av > 0.f) ? expf(av) : 0.f;
}

// ------- per-node: deg, degc -> w_s, dis; ALSO emits slot-ordered wrev[t] = we[REV(eid)] -------
__global__ __launch_bounds__(256) void nodeB_k(const float* __restrict__ we, const int* __restrict__ row_start,
                                               const int2* __restrict__ csr,
                                               float* __restrict__ w_s, float* __restrict__ dis,
                                               float* __restrict__ wrev) {
    int g = blockIdx.x * 256 + threadIdx.x;
    int j = g >> 2, l = g & 3;
    if (j >= N_NODES) return;
    int e0 = row_start[j], e1 = row_start[j + 1];
    float c = 0.f, s = 0.f;
    for (int t = e0 + l; t < e1; t += 4) {
        int eid = csr[t].y;
        float wr = we[REV(eid)];            // surviving in-edge weight
        wrev[t] = wr;                       // slot-ordered for the agg loops
        c += (we[eid] > 0.f) ? 1.f : 0.f;   // deg: surviving out-edges
        s += wr;                            // degc
    }
    c += __shfl_xor(c, 1); c += __shfl_xor(c, 2);
    s += __shfl_xor(s, 1); s += __shfl_xor(s, 2);
    if (l == 0) {
        float ws = expf(1.f / (c + 1.f));
        w_s[j] = ws;
        dis[j] = 1.f / sqrtf(s + ws + 1.f);
    }
}

// ---------------- CSR build (by src) ----------------
__global__ __launch_bounds__(256) void count_k(const int* __restrict__ src, int* __restrict__ cnt) {
    int e = blockIdx.x * 256 + threadIdx.x;
    if (e < E_TOT) atomicAdd(&cnt[src[e]], 1);
}

__global__ __launch_bounds__(1024) void scan1_k(const int* __restrict__ cnt, int* __restrict__ bsum) {
    int i = blockIdx.x * SCAN_T + threadIdx.x;
    int v = (i < N_NODES) ? cnt[i] : 0;
#pragma unroll
    for (int off = 32; off; off >>= 1) v += __shfl_xor(v, off);
    __shared__ int wsm[16];
    int lane = threadIdx.x & 63, wid = threadIdx.x >> 6;
    if (lane == 0) wsm[wid] = v;
    __syncthreads();
    if (threadIdx.x == 0) {
        int s = 0;
#pragma unroll
        for (int k = 0; k < 16; ++k) s += wsm[k];
        bsum[blockIdx.x] = s;
    }
}

__global__ __launch_bounds__(128) void scan2_k(int* __restrict__ bsum) {
    __shared__ int tmp[128];
    int t = threadIdx.x;
    int v = (t < SCAN_NB) ? bsum[t] : 0;
    tmp[t] = v;
    __syncthreads();
    for (int off = 1; off < 128; off <<= 1) {
        int add = (t >= off) ? tmp[t - off] : 0;
        __syncthreads();
        tmp[t] += add;
        __syncthreads();
    }
    if (t < SCAN_NB) bsum[t] = (t > 0) ? tmp[t - 1] : 0;
}

__global__ __launch_bounds__(1024) void scan3_k(const int* __restrict__ cnt, const int* __restrict__ bsum,
                                                int* __restrict__ row_start) {
    int i = blockIdx.x * SCAN_T + threadIdx.x;
    int v = (i < N_NODES) ? cnt[i] : 0;
    int lane = threadIdx.x & 63, wid = threadIdx.x >> 6;
    int x = v;
#pragma unroll
    for (int off = 1; off < 64; off <<= 1) {
        int y = __shfl_up(x, off);
        if (lane >= off) x += y;
    }
    __shared__ int wsum[16], woff[16];
    if (lane == 63) wsum[wid] = x;
    __syncthreads();
    if (threadIdx.x == 0) {
        int s = 0;
#pragma unroll
        for (int k = 0; k < 16; ++k) { woff[k] = s; s += wsum[k]; }
    }
    __syncthreads();
    int excl = (x - v) + woff[wid] + bsum[blockIdx.x];
    if (i < N_NODES) row_start[i] = excl;
    if (i == N_NODES - 1) row_start[N_NODES] = excl + v;
}

// packed scatter: one 8B store per slot (half the dirty lines of two 4B stores)
__global__ __launch_bounds__(256) void fill_k(const int* __restrict__ src, const int* __restrict__ dst,
                                              const int* __restrict__ row_start, int* __restrict__ cursor,
                                              int2* __restrict__ csr) {
    int e = blockIdx.x * 256 + threadIdx.x;
    if (e >= E_TOT) return;
    int s = src[e];
    int p = atomicAdd(&cursor[s], 1);
    csr[row_start[s] + p] = make_int2(dst[e], e);
}

// ---------------- GEMM1: x[N,128] @ W1[128,64] ----------------
__global__ __launch_bounds__(256) void gemm1_k(const float* __restrict__ X, const float* __restrict__ W,
                                               float* __restrict__ Y) {
    __shared__ float sXT[8][128];
    __shared__ float sW[8][64];
    int tid = threadIdx.x;
    int row0 = blockIdx.x * 128;
    int tc = tid & 15;
    int tr = tid >> 4;
    float acc[8][4] = {};
    int lrow = tid >> 1, lhalf = tid & 1;
    int grow = row0 + lrow;
    for (int k0 = 0; k0 < NFEAT; k0 += 8) {
        float4 v = make_float4(0.f, 0.f, 0.f, 0.f);
        if (grow < N_NODES) v = *(const float4*)(X + (size_t)grow * NFEAT + k0 + lhalf * 4);
        sXT[lhalf * 4 + 0][lrow] = v.x;
        sXT[lhalf * 4 + 1][lrow] = v.y;
        sXT[lhalf * 4 + 2][lrow] = v.z;
        sXT[lhalf * 4 + 3][lrow] = v.w;
        float2 wv2 = *(const float2*)(W + (size_t)(k0 + (tid >> 5)) * NHID + (tid & 31) * 2);
        *(float2*)&sW[tid >> 5][(tid & 31) * 2] = wv2;
        __syncthreads();
#pragma unroll
        for (int k = 0; k < 8; ++k) {
            float4 xa = *(const float4*)&sXT[k][tr * 8];
            float4 xb = *(const float4*)&sXT[k][tr * 8 + 4];
            float4 wv = *(const float4*)&sW[k][tc * 4];
            float xr[8] = {xa.x, xa.y, xa.z, xa.w, xb.x, xb.y, xb.z, xb.w};
            float wr[4] = {wv.x, wv.y, wv.z, wv.w};
#pragma unroll
            for (int i = 0; i < 8; ++i)
#pragma unroll
                for (int jj = 0; jj < 4; ++jj)
                    acc[i][jj] = fmaf(xr[i], wr[jj], acc[i][jj]);
        }
        __syncthreads();
    }
#pragma unroll
    for (int i = 0; i < 8; ++i) {
        int r = row0 + tr * 8 + i;
        if (r < N_NODES)
            *(float4*)(Y + (size_t)r * NHID + tc * 4) =
                make_float4(acc[i][0], acc[i][1], acc[i][2], acc[i][3]);
    }
}

// ---------------- GEMM2: h[N,64] @ W2[64,40] ----------------
__global__ __launch_bounds__(256) void gemm2_k(const float* __restrict__ X, const float* __restrict__ W,
                                               float* __restrict__ Y) {
    __shared__ float sXT[8][128];
    __shared__ float sW[320];
    int tid = threadIdx.x;
    int row0 = blockIdx.x * 128;
    int tc = tid & 7;
    int tr = tid >> 3;
    float acc[4][5] = {};
    int lrow = tid >> 1, lhalf = tid & 1;
    int grow = row0 + lrow;
    for (int k0 = 0; k0 < NHID; k0 += 8) {
        float4 v = make_float4(0.f, 0.f, 0.f, 0.f);
        if (grow < N_NODES) v = *(const float4*)(X + (size_t)grow * NHID + k0 + lhalf * 4);
        sXT[lhalf * 4 + 0][lrow] = v.x;
        sXT[lhalf * 4 + 1][lrow] = v.y;
        sXT[lhalf * 4 + 2][lrow] = v.z;
        sXT[lhalf * 4 + 3][lrow] = v.w;
        if (tid < 160) {
            float2 w2 = *(const float2*)(W + k0 * NCLS + tid * 2);
            sW[tid * 2] = w2.x; sW[tid * 2 + 1] = w2.y;
        }
        __syncthreads();
#pragma unroll
        for (int k = 0; k < 8; ++k) {
            float4 xv = *(const float4*)&sXT[k][tr * 4];
            float xr[4] = {xv.x, xv.y, xv.z, xv.w};
            float wr[5];
#pragma unroll
            for (int jj = 0; jj < 5; ++jj) wr[jj] = sW[k * NCLS + tc * 5 + jj];
#pragma unroll
            for (int i = 0; i < 4; ++i)
#pragma unroll
                for (int jj = 0; jj < 5; ++jj)
                    acc[i][jj] = fmaf(xr[i], wr[jj], acc[i][jj]);
        }
        __syncthreads();
    }
#pragma unroll
    for (int i = 0; i < 4; ++i) {
        int r = row0 + tr * 4 + i;
        if (r < N_NODES) {
#pragma unroll
            for (int jj = 0; jj < 5; ++jj) Y[(size_t)r * NCLS + tc * 5 + jj] = acc[i][jj];
        }
    }
}

// -------- aggregation layer 1: branchless unroll-8, slot-ordered wrev, fused row-norm --------
__global__ __launch_bounds__(256) void agg1_k(const float* __restrict__ hpre, const int* __restrict__ row_start,
                                              const int2* __restrict__ csr, const float* __restrict__ wrev,
                                              const float* __restrict__ dis, const float* __restrict__ w_s,
                                              const float* __restrict__ b, float* __restrict__ h,
                                              float* __restrict__ nrm) {
    int j = (blockIdx.x * 256 + threadIdx.x) >> 6;
    int lane = threadIdx.x & 63;
    if (j >= N_NODES) return;
    int e0 = row_start[j], e1 = row_start[j + 1];
    float acc = 0.f;
    for (int t0 = e0; t0 < e1; t0 += 8) {
        float w[8], v[8];
#pragma unroll
        for (int k = 0; k < 8; ++k) {
            int tt = t0 + k;
            bool ok = tt < e1;
            int ts = ok ? tt : (e1 - 1);
            int2 c = csr[ts];
            w[k] = ok ? dis[c.x] * wrev[ts] : 0.f;
            v[k] = hpre[(size_t)c.x * NHID + lane];
        }
#pragma unroll
        for (int k = 0; k < 8; ++k) acc = fmaf(w[k], v[k], acc);
    }
    float dj = dis[j];
    acc = fmaf(dj * (w_s[j] + 1.f), hpre[(size_t)j * NHID + lane], acc);
    float v = fmaxf(fmaf(acc, dj, b[lane]), 0.f);
    h[(size_t)j * NHID + lane] = v;
    float s = v * v;                         // fused row_norm for pass 2
#pragma unroll
    for (int off = 32; off; off >>= 1) s += __shfl_xor(s, off);
    if (lane == 0) nrm[j] = sqrtf(s);
}

// -------- aggregation layer 2 + log_softmax: branchless unroll-8, slot-ordered wrev --------
__global__ __launch_bounds__(256) void agg2_k(const float* __restrict__ hp2, const int* __restrict__ row_start,
                                              const int2* __restrict__ csr, const float* __restrict__ wrev,
                                              const float* __restrict__ dis, const float* __restrict__ w_s,
                                              const float* __restrict__ b, float* __restrict__ out) {
    int j = (blockIdx.x * 256 + threadIdx.x) >> 6;
    int lane = threadIdx.x & 63;
    if (j >= N_NODES) return;
    int lc = (lane < NCLS) ? lane : (NCLS - 1);   // clamped gather lane (same cachelines)
    int e0 = row_start[j], e1 = row_start[j + 1];
    float acc = 0.f;
    for (int t0 = e0; t0 < e1; t0 += 8) {
        float w[8], v[8];
#pragma unroll
        for (int k = 0; k < 8; ++k) {
            int tt = t0 + k;
            bool ok = tt < e1;
            int ts = ok ? tt : (e1 - 1);
            int2 c = csr[ts];
            w[k] = ok ? dis[c.x] * wrev[ts] : 0.f;
            v[k] = hp2[(size_t)c.x * NCLS + lc];
        }
#pragma unroll
        for (int k = 0; k < 8; ++k) acc = fmaf(w[k], v[k], acc);
    }
    float dj = dis[j];
    acc = fmaf(dj * (w_s[j] + 1.f), hp2[(size_t)j * NCLS + lc], acc);
    float v = (lane < NCLS) ? fmaf(acc, dj, b[lane]) : -1e30f;
    float m = v;
#pragma unroll
    for (int off = 32; off; off >>= 1) m = fmaxf(m, __shfl_xor(m, off));
    float ex = (lane < NCLS) ? expf(v - m) : 0.f;
    float ssum = ex;
#pragma unroll
    for (int off = 32; off; off >>= 1) ssum += __shfl_xor(ssum, off);
    if (lane < NCLS) out[(size_t)j * NCLS + lane] = v - m - logf(ssum);
}

extern "C" void kernel_launch(void* const* d_in, const int* in_sizes, int n_in,
                              void* d_out, int out_size, void* d_ws, size_t ws_size,
                              hipStream_t stream) {
    (void)in_sizes; (void)n_in; (void)out_size; (void)ws_size;
    const float* x  = (const float*)d_in[0];
    const int*   src = (const int*)d_in[1];
    const int*   dst = (const int*)d_in[2];
    const float* W1 = (const float*)d_in[4];
    const float* b1 = (const float*)d_in[5];
    const float* W2 = (const float*)d_in[6];
    const float* b2 = (const float*)d_in[7];
    const float* Wd = (const float*)d_in[8];
    const float* bd = (const float*)d_in[9];
    float* out = (float*)d_out;

    char* ws = (char*)d_ws;
    size_t off = 0;
    auto alloc = [&](size_t bytes) -> void* {
        void* p = ws + off;
        off = (off + bytes + 255) & ~(size_t)255;
        return p;
    };
    int*   cnt    = (int*)alloc((size_t)N_NODES * 4);   // doubles as cursor
    float* nrm    = (float*)alloc((size_t)N_NODES * 4);
    float* rowsum = (float*)alloc((size_t)N_NODES * 4);
    float* w_s    = (float*)alloc((size_t)N_NODES * 4);
    float* dis    = (float*)alloc((size_t)N_NODES * 4);
    float* sbuf   = (float*)alloc((size_t)E_TOT * 4);   // raw masked sim values
    float* we1    = (float*)alloc((size_t)E_TOT * 4);
    float* we2    = (float*)alloc((size_t)E_TOT * 4);
    float* wrev   = (float*)alloc((size_t)E_TOT * 4);   // slot-ordered in-edge weights
    float* hpre   = (float*)alloc((size_t)N_NODES * NHID * 4);
    float* h      = (float*)alloc((size_t)N_NODES * NHID * 4);
    int*  row_start = (int*)alloc((size_t)(N_NODES + 1) * 4);
    int2* csr       = (int2*)alloc((size_t)E_TOT * 8);
    int*  bsum      = (int*)alloc(256 * 4);

    const int BE = (E_TOT + 255) / 256;
    const int BW = (N_NODES * 64 + 255) / 256;
    const int BQ = (N_NODES * 4 + 255) / 256;
    const int BS = (E_HALF * 16 + 255) / 256;
    const int BG = (N_NODES + 127) / 128;

    // CSR by src (topology shared by both layers; symmetric graph)
    hipMemsetAsync(cnt, 0, (size_t)N_NODES * 4, stream);
    count_k<<<BE, 256, 0, stream>>>(src, cnt);
    scan1_k<<<SCAN_NB, 1024, 0, stream>>>(cnt, bsum);
    scan2_k<<<1, 128, 0, stream>>>(bsum);
    scan3_k<<<SCAN_NB, 1024, 0, stream>>>(cnt, bsum, row_start);
    hipMemsetAsync(cnt, 0, (size_t)N_NODES * 4, stream);  // reuse as cursor
    fill_k<<<BE, 256, 0, stream>>>(src, dst, row_start, cnt, csr);

    // ---- pass 1: attention on raw features ----
    row_norm_k<NFEAT><<<BW, 256, 0, stream>>>(x, nrm);
    sim_k<NFEAT, false><<<BS, 256, 0, stream>>>(x, nrm, src, dst, nullptr, sbuf);
    rowsum_k<<<BQ, 256, 0, stream>>>(sbuf, row_start, csr, rowsum);
    keep_k<<<BE, 256, 0, stream>>>(sbuf, src, dst, rowsum, Wd, bd, we1);
    nodeB_k<<<BQ, 256, 0, stream>>>(we1, row_start, csr, w_s, dis, wrev);
    gemm1_k<<<BG, 256, 0, stream>>>(x, W1, hpre);
    agg1_k<<<BW, 256, 0, stream>>>(hpre, row_start, csr, wrev, dis, w_s, b1, h, nrm);

    // ---- pass 2: attention on hidden features ----
    sim_k<NHID, true><<<BS, 256, 0, stream>>>(h, nrm, src, dst, we1, sbuf);
    rowsum_k<<<BQ, 256, 0, stream>>>(sbuf, row_start, csr, rowsum);
    keep_k<<<BE, 256, 0, stream>>>(sbuf, src, dst, rowsum, Wd, bd, we2);
    nodeB_k<<<BQ, 256, 0, stream>>>(we2, row_start, csr, w_s, dis, wrev);
    gemm2_k<<<BG, 256, 0, stream>>>(h, W2, hpre);         // hpre reused as [N,40]
    agg2_k<<<BW, 256, 0, stream>>>(hpre, row_start, csr, wrev, dis, w_s, b2, out);
}

// Round 6
// 591.103 us; speedup vs baseline: 1.1881x; 1.1881x over previous
//
#include <hip/hip_runtime.h>

#define N_NODES 100000
#define E_HALF  500000
#define E_TOT   1000000
#define NFEAT   128
#define NHID    64
#define NCLS    40
#define SCAN_T  1024
#define SCAN_NB 98   // ceil(N_NODES/1024)

// rev is arithmetic by construction: rev = concat(arange+E_HALF, arange)
__device__ __forceinline__ int REV(int e) { return (e < E_HALF) ? e + E_HALF : e - E_HALF; }

// ---------------- node norms (pass-1 only; pass-2 norm fused into agg1) ----------------
template<int D>
__global__ __launch_bounds__(256) void row_norm_k(const float* __restrict__ x, float* __restrict__ nrm) {
    int w = (blockIdx.x * 256 + threadIdx.x) >> 6;
    int lane = threadIdx.x & 63;
    if (w >= N_NODES) return;
    const float* row = x + (size_t)w * D;
    float s = 0.f;
#pragma unroll
    for (int i = 0; i < D / 64; ++i) { float v = row[lane + 64 * i]; s = fmaf(v, v, s); }
#pragma unroll
    for (int off = 32; off; off >>= 1) s += __shfl_xor(s, off);
    if (lane == 0) nrm[w] = sqrtf(s);
}

// ---------------- cosine sim on edge pairs (16 lanes / undirected pair), no atomics ----------------
template<int D, bool MASKED>
__global__ __launch_bounds__(256) void sim_k(const float* __restrict__ f, const float* __restrict__ nrm,
                                             const int* __restrict__ src, const int* __restrict__ dst,
                                             const float* __restrict__ we_mask,
                                             float* __restrict__ sim) {
    int g = blockIdx.x * 256 + threadIdx.x;
    int ep = g >> 4, sl = g & 15;
    if (ep >= E_HALF) return;
    bool m0 = true, m1 = true;
    if (MASKED) {
        m0 = we_mask[ep] > 0.f;
        m1 = we_mask[ep + E_HALF] > 0.f;
        if (!m0 && !m1) {               // both directions dropped in pass 1: skip the row gathers
            if (sl == 0) { sim[ep] = 0.f; sim[ep + E_HALF] = 0.f; }
            return;
        }
    }
    int s = src[ep], d = dst[ep];
    const float* fa = f + (size_t)s * D + sl * (D / 16);
    const float* fb = f + (size_t)d * D + sl * (D / 16);
    float acc = 0.f;
#pragma unroll
    for (int i = 0; i < D / 16; i += 4) {
        float4 va = *(const float4*)(fa + i);
        float4 vb = *(const float4*)(fb + i);
        acc = fmaf(va.x, vb.x, acc); acc = fmaf(va.y, vb.y, acc);
        acc = fmaf(va.z, vb.z, acc); acc = fmaf(va.w, vb.w, acc);
    }
    acc += __shfl_xor(acc, 8); acc += __shfl_xor(acc, 4);
    acc += __shfl_xor(acc, 2); acc += __shfl_xor(acc, 1);
    if (sl == 0) {
        float na = nrm[s]; na = (na == 0.f) ? 1.f : na;
        float nb = nrm[d]; nb = (nb == 0.f) ? 1.f : nb;
        float c = acc / (na * nb);
        float t = (c < 0.1f) ? 0.f : c;      // t >= 0 always
        sim[ep]          = m0 ? t : 0.f;
        sim[ep + E_HALF] = m1 ? t : 0.f;
    }
}

// ---------------- rowsum[j] = sum of sim over out-edges (CSR row j), 4 lanes/node ----------------
__global__ __launch_bounds__(256) void rowsum_k(const float* __restrict__ sim, const int* __restrict__ row_start,
                                                const int2* __restrict__ csr, float* __restrict__ rowsum) {
    int g = blockIdx.x * 256 + threadIdx.x;
    int j = g >> 2, l = g & 3;
    if (j >= N_NODES) return;
    int e0 = row_start[j], e1 = row_start[j + 1];
    float s = 0.f;
    for (int t = e0 + l; t < e1; t += 4) s += sim[csr[t].y];
    s += __shfl_xor(s, 1); s += __shfl_xor(s, 2);
    if (l == 0) rowsum[j] = s;
}

// ---------------- fused L1-normalize + learnable keep/drop -> w_e (pure streaming) ----------------
__global__ __launch_bounds__(256) void keep_k(const float* __restrict__ sim,
                                              const int* __restrict__ src, const int* __restrict__ dst,
                                              const float* __restrict__ rowsum,
                                              const float* __restrict__ Wd, const float* __restrict__ bd,
                                              float* __restrict__ we) {
    int e = blockIdx.x * 256 + threadIdx.x;
    if (e >= E_TOT) return;
    int s = src[e], d = dst[e];
    float rs = rowsum[s]; rs = (rs == 0.f) ? 1.f : rs;
    float rd = rowsum[d]; rd = (rd == 0.f) ? 1.f : rd;      // src[rev[e]] == dst[e]
    float ae = sim[e] / rs;
    float ar = sim[REV(e)] / rd;
    float z = ae * Wd[0] + ar * Wd[1] + bd[0];
    float av = (z > 0.f) ? ae : 0.f;          // sigmoid(z)>0.5 <=> z>0
    we[e] = (av > 0.f) ? expf(av) : 0.f;
}

// ------- per-node: deg, degc -> w_s, dis; ALSO emits slot-ordered wrev[t] = we[REV(eid)] -------
__global__ __launch_bounds__(256) void nodeB_k(const float* __restrict__ we, const int* __restrict__ row_start,
                                               const int2* __restrict__ csr,
                                               float* __restrict__ w_s, float* __restrict__ dis,
                                               float* __restrict__ wrev) {
    int g = blockIdx.x * 256 + threadIdx.x;
    int j = g >> 2, l = g & 3;
    if (j >= N_NODES) return;
    int e0 = row_start[j], e1 = row_start[j + 1];
    float c = 0.f, s = 0.f;
    for (int t = e0 + l; t < e1; t += 4) {
        int eid = csr[t].y;
        float wr = we[REV(eid)];            // surviving in-edge weight
        wrev[t] = wr;                       // slot-ordered for slotw_k
        c += (we[eid] > 0.f) ? 1.f : 0.f;   // deg: surviving out-edges
        s += wr;                            // degc
    }
    c += __shfl_xor(c, 1); c += __shfl_xor(c, 2);
    s += __shfl_xor(s, 1); s += __shfl_xor(s, 2);
    if (l == 0) {
        float ws = expf(1.f / (c + 1.f));
        w_s[j] = ws;
        dis[j] = 1.f / sqrtf(s + ws + 1.f);
    }
}

// ------- pack per-slot {col, dis[col]*wrev} into one 8B float2 for the agg stream -------
__global__ __launch_bounds__(256) void slotw_k(const int2* __restrict__ csr, const float* __restrict__ wrev,
                                               const float* __restrict__ dis, float2* __restrict__ pack) {
    int t = blockIdx.x * 256 + threadIdx.x;
    if (t >= E_TOT) return;
    int col = csr[t].x;
    pack[t] = make_float2(__int_as_float(col), dis[col] * wrev[t]);
}

// ---------------- CSR build (by src) ----------------
__global__ __launch_bounds__(256) void count_k(const int* __restrict__ src, int* __restrict__ cnt) {
    int e = blockIdx.x * 256 + threadIdx.x;
    if (e < E_TOT) atomicAdd(&cnt[src[e]], 1);
}

__global__ __launch_bounds__(1024) void scan1_k(const int* __restrict__ cnt, int* __restrict__ bsum) {
    int i = blockIdx.x * SCAN_T + threadIdx.x;
    int v = (i < N_NODES) ? cnt[i] : 0;
#pragma unroll
    for (int off = 32; off; off >>= 1) v += __shfl_xor(v, off);
    __shared__ int wsm[16];
    int lane = threadIdx.x & 63, wid = threadIdx.x >> 6;
    if (lane == 0) wsm[wid] = v;
    __syncthreads();
    if (threadIdx.x == 0) {
        int s = 0;
#pragma unroll
        for (int k = 0; k < 16; ++k) s += wsm[k];
        bsum[blockIdx.x] = s;
    }
}

__global__ __launch_bounds__(128) void scan2_k(int* __restrict__ bsum) {
    __shared__ int tmp[128];
    int t = threadIdx.x;
    int v = (t < SCAN_NB) ? bsum[t] : 0;
    tmp[t] = v;
    __syncthreads();
    for (int off = 1; off < 128; off <<= 1) {
        int add = (t >= off) ? tmp[t - off] : 0;
        __syncthreads();
        tmp[t] += add;
        __syncthreads();
    }
    if (t < SCAN_NB) bsum[t] = (t > 0) ? tmp[t - 1] : 0;
}

__global__ __launch_bounds__(1024) void scan3_k(const int* __restrict__ cnt, const int* __restrict__ bsum,
                                                int* __restrict__ row_start) {
    int i = blockIdx.x * SCAN_T + threadIdx.x;
    int v = (i < N_NODES) ? cnt[i] : 0;
    int lane = threadIdx.x & 63, wid = threadIdx.x >> 6;
    int x = v;
#pragma unroll
    for (int off = 1; off < 64; off <<= 1) {
        int y = __shfl_up(x, off);
        if (lane >= off) x += y;
    }
    __shared__ int wsum[16], woff[16];
    if (lane == 63) wsum[wid] = x;
    __syncthreads();
    if (threadIdx.x == 0) {
        int s = 0;
#pragma unroll
        for (int k = 0; k < 16; ++k) { woff[k] = s; s += wsum[k]; }
    }
    __syncthreads();
    int excl = (x - v) + woff[wid] + bsum[blockIdx.x];
    if (i < N_NODES) row_start[i] = excl;
    if (i == N_NODES - 1) row_start[N_NODES] = excl + v;
}

// packed scatter: one 8B store per slot (half the dirty lines of two 4B stores)
__global__ __launch_bounds__(256) void fill_k(const int* __restrict__ src, const int* __restrict__ dst,
                                              const int* __restrict__ row_start, int* __restrict__ cursor,
                                              int2* __restrict__ csr) {
    int e = blockIdx.x * 256 + threadIdx.x;
    if (e >= E_TOT) return;
    int s = src[e];
    int p = atomicAdd(&cursor[s], 1);
    csr[row_start[s] + p] = make_int2(dst[e], e);
}

// ---------------- GEMM1: x[N,128] @ W1[128,64] ----------------
__global__ __launch_bounds__(256) void gemm1_k(const float* __restrict__ X, const float* __restrict__ W,
                                               float* __restrict__ Y) {
    __shared__ float sXT[8][128];
    __shared__ float sW[8][64];
    int tid = threadIdx.x;
    int row0 = blockIdx.x * 128;
    int tc = tid & 15;
    int tr = tid >> 4;
    float acc[8][4] = {};
    int lrow = tid >> 1, lhalf = tid & 1;
    int grow = row0 + lrow;
    for (int k0 = 0; k0 < NFEAT; k0 += 8) {
        float4 v = make_float4(0.f, 0.f, 0.f, 0.f);
        if (grow < N_NODES) v = *(const float4*)(X + (size_t)grow * NFEAT + k0 + lhalf * 4);
        sXT[lhalf * 4 + 0][lrow] = v.x;
        sXT[lhalf * 4 + 1][lrow] = v.y;
        sXT[lhalf * 4 + 2][lrow] = v.z;
        sXT[lhalf * 4 + 3][lrow] = v.w;
        float2 wv2 = *(const float2*)(W + (size_t)(k0 + (tid >> 5)) * NHID + (tid & 31) * 2);
        *(float2*)&sW[tid >> 5][(tid & 31) * 2] = wv2;
        __syncthreads();
#pragma unroll
        for (int k = 0; k < 8; ++k) {
            float4 xa = *(const float4*)&sXT[k][tr * 8];
            float4 xb = *(const float4*)&sXT[k][tr * 8 + 4];
            float4 wv = *(const float4*)&sW[k][tc * 4];
            float xr[8] = {xa.x, xa.y, xa.z, xa.w, xb.x, xb.y, xb.z, xb.w};
            float wr[4] = {wv.x, wv.y, wv.z, wv.w};
#pragma unroll
            for (int i = 0; i < 8; ++i)
#pragma unroll
                for (int jj = 0; jj < 4; ++jj)
                    acc[i][jj] = fmaf(xr[i], wr[jj], acc[i][jj]);
        }
        __syncthreads();
    }
#pragma unroll
    for (int i = 0; i < 8; ++i) {
        int r = row0 + tr * 8 + i;
        if (r < N_NODES)
            *(float4*)(Y + (size_t)r * NHID + tc * 4) =
                make_float4(acc[i][0], acc[i][1], acc[i][2], acc[i][3]);
    }
}

// ---------------- GEMM2: h[N,64] @ W2[64,40] ----------------
__global__ __launch_bounds__(256) void gemm2_k(const float* __restrict__ X, const float* __restrict__ W,
                                               float* __restrict__ Y) {
    __shared__ float sXT[8][128];
    __shared__ float sW[320];
    int tid = threadIdx.x;
    int row0 = blockIdx.x * 128;
    int tc = tid & 7;
    int tr = tid >> 3;
    float acc[4][5] = {};
    int lrow = tid >> 1, lhalf = tid & 1;
    int grow = row0 + lrow;
    for (int k0 = 0; k0 < NHID; k0 += 8) {
        float4 v = make_float4(0.f, 0.f, 0.f, 0.f);
        if (grow < N_NODES) v = *(const float4*)(X + (size_t)grow * NHID + k0 + lhalf * 4);
        sXT[lhalf * 4 + 0][lrow] = v.x;
        sXT[lhalf * 4 + 1][lrow] = v.y;
        sXT[lhalf * 4 + 2][lrow] = v.z;
        sXT[lhalf * 4 + 3][lrow] = v.w;
        if (tid < 160) {
            float2 w2 = *(const float2*)(W + k0 * NCLS + tid * 2);
            sW[tid * 2] = w2.x; sW[tid * 2 + 1] = w2.y;
        }
        __syncthreads();
#pragma unroll
        for (int k = 0; k < 8; ++k) {
            float4 xv = *(const float4*)&sXT[k][tr * 4];
            float xr[4] = {xv.x, xv.y, xv.z, xv.w};
            float wr[5];
#pragma unroll
            for (int jj = 0; jj < 5; ++jj) wr[jj] = sW[k * NCLS + tc * 5 + jj];
#pragma unroll
            for (int i = 0; i < 4; ++i)
#pragma unroll
                for (int jj = 0; jj < 5; ++jj)
                    acc[i][jj] = fmaf(xr[i], wr[jj], acc[i][jj]);
        }
        __syncthreads();
    }
#pragma unroll
    for (int i = 0; i < 4; ++i) {
        int r = row0 + tr * 4 + i;
        if (r < N_NODES) {
#pragma unroll
            for (int jj = 0; jj < 5; ++jj) Y[(size_t)r * NCLS + tc * 5 + jj] = acc[i][jj];
        }
    }
}

// -------- aggregation layer 1: packed {col,w} stream, unroll-4 + remainder, fused row-norm --------
__global__ __launch_bounds__(256) void agg1_k(const float* __restrict__ hpre, const int* __restrict__ row_start,
                                              const float2* __restrict__ pack,
                                              const float* __restrict__ dis, const float* __restrict__ w_s,
                                              const float* __restrict__ b, float* __restrict__ h,
                                              float* __restrict__ nrm) {
    int j = (blockIdx.x * 256 + threadIdx.x) >> 6;
    int lane = threadIdx.x & 63;
    if (j >= N_NODES) return;
    int e0 = row_start[j], e1 = row_start[j + 1];
    float acc = 0.f;
    int t = e0;
    for (; t + 4 <= e1; t += 4) {
        float2 p0 = pack[t], p1 = pack[t + 1], p2 = pack[t + 2], p3 = pack[t + 3];
        float v0 = hpre[(size_t)__float_as_int(p0.x) * NHID + lane];
        float v1 = hpre[(size_t)__float_as_int(p1.x) * NHID + lane];
        float v2 = hpre[(size_t)__float_as_int(p2.x) * NHID + lane];
        float v3 = hpre[(size_t)__float_as_int(p3.x) * NHID + lane];
        acc = fmaf(p0.y, v0, acc); acc = fmaf(p1.y, v1, acc);
        acc = fmaf(p2.y, v2, acc); acc = fmaf(p3.y, v3, acc);
    }
    for (; t < e1; ++t) {
        float2 p = pack[t];
        acc = fmaf(p.y, hpre[(size_t)__float_as_int(p.x) * NHID + lane], acc);
    }
    float dj = dis[j];
    acc = fmaf(dj * (w_s[j] + 1.f), hpre[(size_t)j * NHID + lane], acc);
    float v = fmaxf(fmaf(acc, dj, b[lane]), 0.f);
    h[(size_t)j * NHID + lane] = v;
    float s = v * v;                         // fused row_norm for pass 2
#pragma unroll
    for (int off = 32; off; off >>= 1) s += __shfl_xor(s, off);
    if (lane == 0) nrm[j] = sqrtf(s);
}

// -------- aggregation layer 2 + log_softmax: packed {col,w} stream, unroll-4 + remainder --------
__global__ __launch_bounds__(256) void agg2_k(const float* __restrict__ hp2, const int* __restrict__ row_start,
                                              const float2* __restrict__ pack,
                                              const float* __restrict__ dis, const float* __restrict__ w_s,
                                              const float* __restrict__ b, float* __restrict__ out) {
    int j = (blockIdx.x * 256 + threadIdx.x) >> 6;
    int lane = threadIdx.x & 63;
    if (j >= N_NODES) return;
    int lc = (lane < NCLS) ? lane : (NCLS - 1);   // clamped gather lane (same cachelines)
    int e0 = row_start[j], e1 = row_start[j + 1];
    float acc = 0.f;
    int t = e0;
    for (; t + 4 <= e1; t += 4) {
        float2 p0 = pack[t], p1 = pack[t + 1], p2 = pack[t + 2], p3 = pack[t + 3];
        float v0 = hp2[(size_t)__float_as_int(p0.x) * NCLS + lc];
        float v1 = hp2[(size_t)__float_as_int(p1.x) * NCLS + lc];
        float v2 = hp2[(size_t)__float_as_int(p2.x) * NCLS + lc];
        float v3 = hp2[(size_t)__float_as_int(p3.x) * NCLS + lc];
        acc = fmaf(p0.y, v0, acc); acc = fmaf(p1.y, v1, acc);
        acc = fmaf(p2.y, v2, acc); acc = fmaf(p3.y, v3, acc);
    }
    for (; t < e1; ++t) {
        float2 p = pack[t];
        acc = fmaf(p.y, hp2[(size_t)__float_as_int(p.x) * NCLS + lc], acc);
    }
    float dj = dis[j];
    acc = fmaf(dj * (w_s[j] + 1.f), hp2[(size_t)j * NCLS + lc], acc);
    float v = (lane < NCLS) ? fmaf(acc, dj, b[lane]) : -1e30f;
    float m = v;
#pragma unroll
    for (int off = 32; off; off >>= 1) m = fmaxf(m, __shfl_xor(m, off));
    float ex = (lane < NCLS) ? expf(v - m) : 0.f;
    float ssum = ex;
#pragma unroll
    for (int off = 32; off; off >>= 1) ssum += __shfl_xor(ssum, off);
    if (lane < NCLS) out[(size_t)j * NCLS + lane] = v - m - logf(ssum);
}

extern "C" void kernel_launch(void* const* d_in, const int* in_sizes, int n_in,
                              void* d_out, int out_size, void* d_ws, size_t ws_size,
                              hipStream_t stream) {
    (void)in_sizes; (void)n_in; (void)out_size; (void)ws_size;
    const float* x  = (const float*)d_in[0];
    const int*   src = (const int*)d_in[1];
    const int*   dst = (const int*)d_in[2];
    const float* W1 = (const float*)d_in[4];
    const float* b1 = (const float*)d_in[5];
    const float* W2 = (const float*)d_in[6];
    const float* b2 = (const float*)d_in[7];
    const float* Wd = (const float*)d_in[8];
    const float* bd = (const float*)d_in[9];
    float* out = (float*)d_out;

    char* ws = (char*)d_ws;
    size_t off = 0;
    auto alloc = [&](size_t bytes) -> void* {
        void* p = ws + off;
        off = (off + bytes + 255) & ~(size_t)255;
        return p;
    };
    int*   cnt    = (int*)alloc((size_t)N_NODES * 4);   // doubles as cursor
    float* nrm    = (float*)alloc((size_t)N_NODES * 4);
    float* rowsum = (float*)alloc((size_t)N_NODES * 4);
    float* w_s    = (float*)alloc((size_t)N_NODES * 4);
    float* dis    = (float*)alloc((size_t)N_NODES * 4);
    float* sbuf   = (float*)alloc((size_t)E_TOT * 4);   // raw masked sim values
    float* we1    = (float*)alloc((size_t)E_TOT * 4);
    float* we2    = (float*)alloc((size_t)E_TOT * 4);
    float* wrev   = (float*)alloc((size_t)E_TOT * 4);   // slot-ordered in-edge weights
    float2* pack  = (float2*)alloc((size_t)E_TOT * 8);  // {col, dis[col]*wrev}
    float* hpre   = (float*)alloc((size_t)N_NODES * NHID * 4);
    float* h      = (float*)alloc((size_t)N_NODES * NHID * 4);
    int*  row_start = (int*)alloc((size_t)(N_NODES + 1) * 4);
    int2* csr       = (int2*)alloc((size_t)E_TOT * 8);
    int*  bsum      = (int*)alloc(256 * 4);

    const int BE = (E_TOT + 255) / 256;
    const int BW = (N_NODES * 64 + 255) / 256;
    const int BQ = (N_NODES * 4 + 255) / 256;
    const int BS = (E_HALF * 16 + 255) / 256;
    const int BG = (N_NODES + 127) / 128;

    // CSR by src (topology shared by both layers; symmetric graph)
    hipMemsetAsync(cnt, 0, (size_t)N_NODES * 4, stream);
    count_k<<<BE, 256, 0, stream>>>(src, cnt);
    scan1_k<<<SCAN_NB, 1024, 0, stream>>>(cnt, bsum);
    scan2_k<<<1, 128, 0, stream>>>(bsum);
    scan3_k<<<SCAN_NB, 1024, 0, stream>>>(cnt, bsum, row_start);
    hipMemsetAsync(cnt, 0, (size_t)N_NODES * 4, stream);  // reuse as cursor
    fill_k<<<BE, 256, 0, stream>>>(src, dst, row_start, cnt, csr);

    // ---- pass 1: attention on raw features ----
    row_norm_k<NFEAT><<<BW, 256, 0, stream>>>(x, nrm);
    sim_k<NFEAT, false><<<BS, 256, 0, stream>>>(x, nrm, src, dst, nullptr, sbuf);
    rowsum_k<<<BQ, 256, 0, stream>>>(sbuf, row_start, csr, rowsum);
    keep_k<<<BE, 256, 0, stream>>>(sbuf, src, dst, rowsum, Wd, bd, we1);
    nodeB_k<<<BQ, 256, 0, stream>>>(we1, row_start, csr, w_s, dis, wrev);
    gemm1_k<<<BG, 256, 0, stream>>>(x, W1, hpre);
    slotw_k<<<BE, 256, 0, stream>>>(csr, wrev, dis, pack);
    agg1_k<<<BW, 256, 0, stream>>>(hpre, row_start, pack, dis, w_s, b1, h, nrm);

    // ---- pass 2: attention on hidden features ----
    sim_k<NHID, true><<<BS, 256, 0, stream>>>(h, nrm, src, dst, we1, sbuf);
    rowsum_k<<<BQ, 256, 0, stream>>>(sbuf, row_start, csr, rowsum);
    keep_k<<<BE, 256, 0, stream>>>(sbuf, src, dst, rowsum, Wd, bd, we2);
    nodeB_k<<<BQ, 256, 0, stream>>>(we2, row_start, csr, w_s, dis, wrev);
    gemm2_k<<<BG, 256, 0, stream>>>(h, W2, hpre);         // hpre reused as [N,40]
    slotw_k<<<BE, 256, 0, stream>>>(csr, wrev, dis, pack);
    agg2_k<<<BW, 256, 0, stream>>>(hpre, row_start, pack, dis, w_s, b2, out);
}

// Round 7
// 584.889 us; speedup vs baseline: 1.2008x; 1.0106x over previous
//
#include <hip/hip_runtime.h>

#define N_NODES 100000
#define E_HALF  500000
#define E_TOT   1000000
#define NFEAT   128
#define NHID    64
#define NCLS    40
#define SCAN_T  1024
#define SCAN_NB 98   // ceil(N_NODES/1024)

// rev is arithmetic by construction: rev = concat(arange+E_HALF, arange)
__device__ __forceinline__ int REV(int e) { return (e < E_HALF) ? e + E_HALF : e - E_HALF; }

// ---------------- node norms (pass-1 only; pass-2 norm fused into agg1) ----------------
template<int D>
__global__ __launch_bounds__(256) void row_norm_k(const float* __restrict__ x, float* __restrict__ nrm) {
    int w = (blockIdx.x * 256 + threadIdx.x) >> 6;
    int lane = threadIdx.x & 63;
    if (w >= N_NODES) return;
    const float* row = x + (size_t)w * D;
    float s = 0.f;
#pragma unroll
    for (int i = 0; i < D / 64; ++i) { float v = row[lane + 64 * i]; s = fmaf(v, v, s); }
#pragma unroll
    for (int off = 32; off; off >>= 1) s += __shfl_xor(s, off);
    if (lane == 0) nrm[w] = sqrtf(s);
}

// ------- cosine sim on edge pairs: L lanes/pair, each lane owns one 64B line (16 floats) -------
template<int D, int L, bool MASKED>
__global__ __launch_bounds__(256) void sim_k(const float* __restrict__ f, const float* __restrict__ nrm,
                                             const int* __restrict__ src, const int* __restrict__ dst,
                                             const float* __restrict__ we_mask,
                                             float* __restrict__ sim) {
    static_assert(D / L == 16, "each lane covers 16 floats");
    int g = blockIdx.x * 256 + threadIdx.x;
    int ep = g / L, sl = g % L;
    if (ep >= E_HALF) return;
    bool m0 = true, m1 = true;
    if (MASKED) {
        m0 = we_mask[ep] > 0.f;
        m1 = we_mask[ep + E_HALF] > 0.f;
        if (!m0 && !m1) {               // both directions dropped in pass 1: skip the row gathers
            if (sl == 0) { sim[ep] = 0.f; sim[ep + E_HALF] = 0.f; }
            return;
        }
    }
    int s = src[ep], d = dst[ep];
    const float* fa = f + (size_t)s * D + sl * 16;
    const float* fb = f + (size_t)d * D + sl * 16;
    float acc = 0.f;
#pragma unroll
    for (int i = 0; i < 16; i += 4) {
        float4 va = *(const float4*)(fa + i);
        float4 vb = *(const float4*)(fb + i);
        acc = fmaf(va.x, vb.x, acc); acc = fmaf(va.y, vb.y, acc);
        acc = fmaf(va.z, vb.z, acc); acc = fmaf(va.w, vb.w, acc);
    }
#pragma unroll
    for (int off = L / 2; off; off >>= 1) acc += __shfl_xor(acc, off);
    if (sl == 0) {
        float na = nrm[s]; na = (na == 0.f) ? 1.f : na;
        float nb = nrm[d]; nb = (nb == 0.f) ? 1.f : nb;
        float c = acc / (na * nb);
        float t = (c < 0.1f) ? 0.f : c;      // t >= 0 always
        sim[ep]          = m0 ? t : 0.f;
        sim[ep + E_HALF] = m1 ? t : 0.f;
    }
}

// ---------------- rowsum[j] = sum of sim over out-edges (CSR row j), 4 lanes/node ----------------
__global__ __launch_bounds__(256) void rowsum_k(const float* __restrict__ sim, const int* __restrict__ row_start,
                                                const int2* __restrict__ csr, float* __restrict__ rowsum) {
    int g = blockIdx.x * 256 + threadIdx.x;
    int j = g >> 2, l = g & 3;
    if (j >= N_NODES) return;
    int e0 = row_start[j], e1 = row_start[j + 1];
    float s = 0.f;
    for (int t = e0 + l; t < e1; t += 4) s += sim[csr[t].y];
    s += __shfl_xor(s, 1); s += __shfl_xor(s, 2);
    if (l == 0) rowsum[j] = s;
}

// ---------------- fused L1-normalize + learnable keep/drop -> w_e (pure streaming) ----------------
__global__ __launch_bounds__(256) void keep_k(const float* __restrict__ sim,
                                              const int* __restrict__ src, const int* __restrict__ dst,
                                              const float* __restrict__ rowsum,
                                              const float* __restrict__ Wd, const float* __restrict__ bd,
                                              float* __restrict__ we) {
    int e = blockIdx.x * 256 + threadIdx.x;
    if (e >= E_TOT) return;
    int s = src[e], d = dst[e];
    float rs = rowsum[s]; rs = (rs == 0.f) ? 1.f : rs;
    float rd = rowsum[d]; rd = (rd == 0.f) ? 1.f : rd;      // src[rev[e]] == dst[e]
    float ae = sim[e] / rs;
    float ar = sim[REV(e)] / rd;
    float z = ae * Wd[0] + ar * Wd[1] + bd[0];
    float av = (z > 0.f) ? ae : 0.f;          // sigmoid(z)>0.5 <=> z>0
    we[e] = (av > 0.f) ? expf(av) : 0.f;
}

// ------- per-node: deg, degc -> w_s, dis; ALSO emits slot-ordered wrev[t] = we[REV(eid)] -------
__global__ __launch_bounds__(256) void nodeB_k(const float* __restrict__ we, const int* __restrict__ row_start,
                                               const int2* __restrict__ csr,
                                               float* __restrict__ w_s, float* __restrict__ dis,
                                               float* __restrict__ wrev) {
    int g = blockIdx.x * 256 + threadIdx.x;
    int j = g >> 2, l = g & 3;
    if (j >= N_NODES) return;
    int e0 = row_start[j], e1 = row_start[j + 1];
    float c = 0.f, s = 0.f;
    for (int t = e0 + l; t < e1; t += 4) {
        int eid = csr[t].y;
        float wr = we[REV(eid)];            // surviving in-edge weight
        wrev[t] = wr;                       // slot-ordered for the agg loops
        c += (we[eid] > 0.f) ? 1.f : 0.f;   // deg: surviving out-edges
        s += wr;                            // degc
    }
    c += __shfl_xor(c, 1); c += __shfl_xor(c, 2);
    s += __shfl_xor(s, 1); s += __shfl_xor(s, 2);
    if (l == 0) {
        float ws = expf(1.f / (c + 1.f));
        w_s[j] = ws;
        dis[j] = 1.f / sqrtf(s + ws + 1.f);
    }
}

// ---------------- CSR build (by src) ----------------
__global__ __launch_bounds__(256) void count_k(const int* __restrict__ src, int* __restrict__ cnt) {
    int e = blockIdx.x * 256 + threadIdx.x;
    if (e < E_TOT) atomicAdd(&cnt[src[e]], 1);
}

__global__ __launch_bounds__(1024) void scan1_k(const int* __restrict__ cnt, int* __restrict__ bsum) {
    int i = blockIdx.x * SCAN_T + threadIdx.x;
    int v = (i < N_NODES) ? cnt[i] : 0;
#pragma unroll
    for (int off = 32; off; off >>= 1) v += __shfl_xor(v, off);
    __shared__ int wsm[16];
    int lane = threadIdx.x & 63, wid = threadIdx.x >> 6;
    if (lane == 0) wsm[wid] = v;
    __syncthreads();
    if (threadIdx.x == 0) {
        int s = 0;
#pragma unroll
        for (int k = 0; k < 16; ++k) s += wsm[k];
        bsum[blockIdx.x] = s;
    }
}

__global__ __launch_bounds__(128) void scan2_k(int* __restrict__ bsum) {
    __shared__ int tmp[128];
    int t = threadIdx.x;
    int v = (t < SCAN_NB) ? bsum[t] : 0;
    tmp[t] = v;
    __syncthreads();
    for (int off = 1; off < 128; off <<= 1) {
        int add = (t >= off) ? tmp[t - off] : 0;
        __syncthreads();
        tmp[t] += add;
        __syncthreads();
    }
    if (t < SCAN_NB) bsum[t] = (t > 0) ? tmp[t - 1] : 0;
}

__global__ __launch_bounds__(1024) void scan3_k(const int* __restrict__ cnt, const int* __restrict__ bsum,
                                                int* __restrict__ row_start) {
    int i = blockIdx.x * SCAN_T + threadIdx.x;
    int v = (i < N_NODES) ? cnt[i] : 0;
    int lane = threadIdx.x & 63, wid = threadIdx.x >> 6;
    int x = v;
#pragma unroll
    for (int off = 1; off < 64; off <<= 1) {
        int y = __shfl_up(x, off);
        if (lane >= off) x += y;
    }
    __shared__ int wsum[16], woff[16];
    if (lane == 63) wsum[wid] = x;
    __syncthreads();
    if (threadIdx.x == 0) {
        int s = 0;
#pragma unroll
        for (int k = 0; k < 16; ++k) { woff[k] = s; s += wsum[k]; }
    }
    __syncthreads();
    int excl = (x - v) + woff[wid] + bsum[blockIdx.x];
    if (i < N_NODES) row_start[i] = excl;
    if (i == N_NODES - 1) row_start[N_NODES] = excl + v;
}

// packed NON-TEMPORAL scatter: one 8B store per slot, bypassing L2 write-allocate/bounce
__global__ __launch_bounds__(256) void fill_k(const int* __restrict__ src, const int* __restrict__ dst,
                                              const int* __restrict__ row_start, int* __restrict__ cursor,
                                              int2* __restrict__ csr) {
    int e = blockIdx.x * 256 + threadIdx.x;
    if (e >= E_TOT) return;
    int s = src[e];
    int p = atomicAdd(&cursor[s], 1);
    long long packed = ((long long)(unsigned)e << 32) | (unsigned)dst[e];  // .x=col, .y=eid
    __builtin_nontemporal_store(packed, (long long*)(csr + row_start[s] + p));
}

// ---------------- GEMM1: hs = (x[N,128] @ W1[128,64]) * dis[row] ----------------
__global__ __launch_bounds__(256) void gemm1_k(const float* __restrict__ X, const float* __restrict__ W,
                                               const float* __restrict__ dis, float* __restrict__ Y) {
    __shared__ float sXT[8][128];
    __shared__ float sW[8][64];
    int tid = threadIdx.x;
    int row0 = blockIdx.x * 128;
    int tc = tid & 15;
    int tr = tid >> 4;
    float acc[8][4] = {};
    int lrow = tid >> 1, lhalf = tid & 1;
    int grow = row0 + lrow;
    for (int k0 = 0; k0 < NFEAT; k0 += 8) {
        float4 v = make_float4(0.f, 0.f, 0.f, 0.f);
        if (grow < N_NODES) v = *(const float4*)(X + (size_t)grow * NFEAT + k0 + lhalf * 4);
        sXT[lhalf * 4 + 0][lrow] = v.x;
        sXT[lhalf * 4 + 1][lrow] = v.y;
        sXT[lhalf * 4 + 2][lrow] = v.z;
        sXT[lhalf * 4 + 3][lrow] = v.w;
        float2 wv2 = *(const float2*)(W + (size_t)(k0 + (tid >> 5)) * NHID + (tid & 31) * 2);
        *(float2*)&sW[tid >> 5][(tid & 31) * 2] = wv2;
        __syncthreads();
#pragma unroll
        for (int k = 0; k < 8; ++k) {
            float4 xa = *(const float4*)&sXT[k][tr * 8];
            float4 xb = *(const float4*)&sXT[k][tr * 8 + 4];
            float4 wv = *(const float4*)&sW[k][tc * 4];
            float xr[8] = {xa.x, xa.y, xa.z, xa.w, xb.x, xb.y, xb.z, xb.w};
            float wr[4] = {wv.x, wv.y, wv.z, wv.w};
#pragma unroll
            for (int i = 0; i < 8; ++i)
#pragma unroll
                for (int jj = 0; jj < 4; ++jj)
                    acc[i][jj] = fmaf(xr[i], wr[jj], acc[i][jj]);
        }
        __syncthreads();
    }
#pragma unroll
    for (int i = 0; i < 8; ++i) {
        int r = row0 + tr * 8 + i;
        if (r < N_NODES) {
            float dr = dis[r];
            *(float4*)(Y + (size_t)r * NHID + tc * 4) =
                make_float4(acc[i][0] * dr, acc[i][1] * dr, acc[i][2] * dr, acc[i][3] * dr);
        }
    }
}

// ---------------- GEMM2: hs2 = (h[N,64] @ W2[64,40]) * dis[row] ----------------
__global__ __launch_bounds__(256) void gemm2_k(const float* __restrict__ X, const float* __restrict__ W,
                                               const float* __restrict__ dis, float* __restrict__ Y) {
    __shared__ float sXT[8][128];
    __shared__ float sW[320];
    int tid = threadIdx.x;
    int row0 = blockIdx.x * 128;
    int tc = tid & 7;
    int tr = tid >> 3;
    float acc[4][5] = {};
    int lrow = tid >> 1, lhalf = tid & 1;
    int grow = row0 + lrow;
    for (int k0 = 0; k0 < NHID; k0 += 8) {
        float4 v = make_float4(0.f, 0.f, 0.f, 0.f);
        if (grow < N_NODES) v = *(const float4*)(X + (size_t)grow * NHID + k0 + lhalf * 4);
        sXT[lhalf * 4 + 0][lrow] = v.x;
        sXT[lhalf * 4 + 1][lrow] = v.y;
        sXT[lhalf * 4 + 2][lrow] = v.z;
        sXT[lhalf * 4 + 3][lrow] = v.w;
        if (tid < 160) {
            float2 w2 = *(const float2*)(W + k0 * NCLS + tid * 2);
            sW[tid * 2] = w2.x; sW[tid * 2 + 1] = w2.y;
        }
        __syncthreads();
#pragma unroll
        for (int k = 0; k < 8; ++k) {
            float4 xv = *(const float4*)&sXT[k][tr * 4];
            float xr[4] = {xv.x, xv.y, xv.z, xv.w};
            float wr[5];
#pragma unroll
            for (int jj = 0; jj < 5; ++jj) wr[jj] = sW[k * NCLS + tc * 5 + jj];
#pragma unroll
            for (int i = 0; i < 4; ++i)
#pragma unroll
                for (int jj = 0; jj < 5; ++jj)
                    acc[i][jj] = fmaf(xr[i], wr[jj], acc[i][jj]);
        }
        __syncthreads();
    }
#pragma unroll
    for (int i = 0; i < 4; ++i) {
        int r = row0 + tr * 4 + i;
        if (r < N_NODES) {
            float dr = dis[r];
#pragma unroll
            for (int jj = 0; jj < 5; ++jj) Y[(size_t)r * NCLS + tc * 5 + jj] = acc[i][jj] * dr;
        }
    }
}

// -------- aggregation layer 1 on dis-scaled hs: acc=SUM wrev*hs[col]+(w_s+1)*hs[j]; out=acc*dis[j]+b --------
__global__ __launch_bounds__(256) void agg1_k(const float* __restrict__ hs, const int* __restrict__ row_start,
                                              const int2* __restrict__ csr, const float* __restrict__ wrev,
                                              const float* __restrict__ dis, const float* __restrict__ w_s,
                                              const float* __restrict__ b, float* __restrict__ h,
                                              float* __restrict__ nrm) {
    int j = (blockIdx.x * 256 + threadIdx.x) >> 6;
    int lane = threadIdx.x & 63;
    if (j >= N_NODES) return;
    int e0 = row_start[j], e1 = row_start[j + 1];
    float acc = 0.f;
    int t = e0;
    for (; t + 4 <= e1; t += 4) {
        int2 c0 = csr[t], c1 = csr[t + 1], c2 = csr[t + 2], c3 = csr[t + 3];
        float w0 = wrev[t], w1 = wrev[t + 1], w2 = wrev[t + 2], w3 = wrev[t + 3];
        float v0 = hs[(size_t)c0.x * NHID + lane];
        float v1 = hs[(size_t)c1.x * NHID + lane];
        float v2 = hs[(size_t)c2.x * NHID + lane];
        float v3 = hs[(size_t)c3.x * NHID + lane];
        acc = fmaf(w0, v0, acc); acc = fmaf(w1, v1, acc);
        acc = fmaf(w2, v2, acc); acc = fmaf(w3, v3, acc);
    }
    for (; t < e1; ++t)
        acc = fmaf(wrev[t], hs[(size_t)csr[t].x * NHID + lane], acc);
    acc = fmaf(w_s[j] + 1.f, hs[(size_t)j * NHID + lane], acc);
    float v = fmaxf(fmaf(acc, dis[j], b[lane]), 0.f);
    h[(size_t)j * NHID + lane] = v;
    float s = v * v;                         // fused row_norm for pass 2
#pragma unroll
    for (int off = 32; off; off >>= 1) s += __shfl_xor(s, off);
    if (lane == 0) nrm[j] = sqrtf(s);
}

// -------- aggregation layer 2 + log_softmax on dis-scaled hs2 --------
__global__ __launch_bounds__(256) void agg2_k(const float* __restrict__ hs2, const int* __restrict__ row_start,
                                              const int2* __restrict__ csr, const float* __restrict__ wrev,
                                              const float* __restrict__ dis, const float* __restrict__ w_s,
                                              const float* __restrict__ b, float* __restrict__ out) {
    int j = (blockIdx.x * 256 + threadIdx.x) >> 6;
    int lane = threadIdx.x & 63;
    if (j >= N_NODES) return;
    int lc = (lane < NCLS) ? lane : (NCLS - 1);   // clamped gather lane (same cachelines)
    int e0 = row_start[j], e1 = row_start[j + 1];
    float acc = 0.f;
    int t = e0;
    for (; t + 4 <= e1; t += 4) {
        int2 c0 = csr[t], c1 = csr[t + 1], c2 = csr[t + 2], c3 = csr[t + 3];
        float w0 = wrev[t], w1 = wrev[t + 1], w2 = wrev[t + 2], w3 = wrev[t + 3];
        float v0 = hs2[(size_t)c0.x * NCLS + lc];
        float v1 = hs2[(size_t)c1.x * NCLS + lc];
        float v2 = hs2[(size_t)c2.x * NCLS + lc];
        float v3 = hs2[(size_t)c3.x * NCLS + lc];
        acc = fmaf(w0, v0, acc); acc = fmaf(w1, v1, acc);
        acc = fmaf(w2, v2, acc); acc = fmaf(w3, v3, acc);
    }
    for (; t < e1; ++t)
        acc = fmaf(wrev[t], hs2[(size_t)csr[t].x * NCLS + lc], acc);
    acc = fmaf(w_s[j] + 1.f, hs2[(size_t)j * NCLS + lc], acc);
    float v = (lane < NCLS) ? fmaf(acc, dis[j], b[lane]) : -1e30f;
    float m = v;
#pragma unroll
    for (int off = 32; off; off >>= 1) m = fmaxf(m, __shfl_xor(m, off));
    float ex = (lane < NCLS) ? expf(v - m) : 0.f;
    float ssum = ex;
#pragma unroll
    for (int off = 32; off; off >>= 1) ssum += __shfl_xor(ssum, off);
    if (lane < NCLS) out[(size_t)j * NCLS + lane] = v - m - logf(ssum);
}

extern "C" void kernel_launch(void* const* d_in, const int* in_sizes, int n_in,
                              void* d_out, int out_size, void* d_ws, size_t ws_size,
                              hipStream_t stream) {
    (void)in_sizes; (void)n_in; (void)out_size; (void)ws_size;
    const float* x  = (const float*)d_in[0];
    const int*   src = (const int*)d_in[1];
    const int*   dst = (const int*)d_in[2];
    const float* W1 = (const float*)d_in[4];
    const float* b1 = (const float*)d_in[5];
    const float* W2 = (const float*)d_in[6];
    const float* b2 = (const float*)d_in[7];
    const float* Wd = (const float*)d_in[8];
    const float* bd = (const float*)d_in[9];
    float* out = (float*)d_out;

    char* ws = (char*)d_ws;
    size_t off = 0;
    auto alloc = [&](size_t bytes) -> void* {
        void* p = ws + off;
        off = (off + bytes + 255) & ~(size_t)255;
        return p;
    };
    size_t z0 = off;
    int*   cnt    = (int*)alloc((size_t)N_NODES * 4);
    int*   cursor = (int*)alloc((size_t)N_NODES * 4);
    size_t z1 = off;                                    // single memset covers cnt+cursor
    float* nrm    = (float*)alloc((size_t)N_NODES * 4);
    float* rowsum = (float*)alloc((size_t)N_NODES * 4);
    float* w_s    = (float*)alloc((size_t)N_NODES * 4);
    float* dis    = (float*)alloc((size_t)N_NODES * 4);
    float* sbuf   = (float*)alloc((size_t)E_TOT * 4);   // raw masked sim values
    float* we1    = (float*)alloc((size_t)E_TOT * 4);
    float* we2    = (float*)alloc((size_t)E_TOT * 4);
    float* wrev   = (float*)alloc((size_t)E_TOT * 4);   // slot-ordered in-edge weights
    float* hs     = (float*)alloc((size_t)N_NODES * NHID * 4);  // dis-scaled gemm output
    float* h      = (float*)alloc((size_t)N_NODES * NHID * 4);
    int*  row_start = (int*)alloc((size_t)(N_NODES + 1) * 4);
    int2* csr       = (int2*)alloc((size_t)E_TOT * 8);
    int*  bsum      = (int*)alloc(256 * 4);

    const int BE  = (E_TOT + 255) / 256;
    const int BW  = (N_NODES * 64 + 255) / 256;
    const int BQ  = (N_NODES * 4 + 255) / 256;
    const int BS8 = (E_HALF * 8 + 255) / 256;
    const int BS4 = (E_HALF * 4 + 255) / 256;
    const int BG  = (N_NODES + 127) / 128;

    // CSR by src (topology shared by both layers; symmetric graph)
    hipMemsetAsync(ws + z0, 0, z1 - z0, stream);        // cnt + cursor
    count_k<<<BE, 256, 0, stream>>>(src, cnt);
    scan1_k<<<SCAN_NB, 1024, 0, stream>>>(cnt, bsum);
    scan2_k<<<1, 128, 0, stream>>>(bsum);
    scan3_k<<<SCAN_NB, 1024, 0, stream>>>(cnt, bsum, row_start);
    fill_k<<<BE, 256, 0, stream>>>(src, dst, row_start, cursor, csr);

    // ---- pass 1: attention on raw features ----
    row_norm_k<NFEAT><<<BW, 256, 0, stream>>>(x, nrm);
    sim_k<NFEAT, 8, false><<<BS8, 256, 0, stream>>>(x, nrm, src, dst, nullptr, sbuf);
    rowsum_k<<<BQ, 256, 0, stream>>>(sbuf, row_start, csr, rowsum);
    keep_k<<<BE, 256, 0, stream>>>(sbuf, src, dst, rowsum, Wd, bd, we1);
    nodeB_k<<<BQ, 256, 0, stream>>>(we1, row_start, csr, w_s, dis, wrev);
    gemm1_k<<<BG, 256, 0, stream>>>(x, W1, dis, hs);
    agg1_k<<<BW, 256, 0, stream>>>(hs, row_start, csr, wrev, dis, w_s, b1, h, nrm);

    // ---- pass 2: attention on hidden features ----
    sim_k<NHID, 4, true><<<BS4, 256, 0, stream>>>(h, nrm, src, dst, we1, sbuf);
    rowsum_k<<<BQ, 256, 0, stream>>>(sbuf, row_start, csr, rowsum);
    keep_k<<<BE, 256, 0, stream>>>(sbuf, src, dst, rowsum, Wd, bd, we2);
    nodeB_k<<<BQ, 256, 0, stream>>>(we2, row_start, csr, w_s, dis, wrev);
    gemm2_k<<<BG, 256, 0, stream>>>(h, W2, dis, hs);      // hs reused as [N,40]
    agg2_k<<<BW, 256, 0, stream>>>(hs, row_start, csr, wrev, dis, w_s, b2, out);
}

// Round 8
// 544.296 us; speedup vs baseline: 1.2903x; 1.0746x over previous
//
#include <hip/hip_runtime.h>

#define N_NODES 100000
#define E_HALF  500000
#define E_TOT   1000000
#define NFEAT   128
#define NHID    64
#define NCLS    40
#define NBUK    782            // ceil(N_NODES/128): 128-node buckets
#define NSUB    8              // sub-streams per bucket (blockIdx&7 ~ XCD class)
#define CAP     448            // slots per (sub,bucket) stream; mean 160, +22 sigma

// rev is arithmetic by construction: rev = concat(arange+E_HALF, arange)
__device__ __forceinline__ int REV(int e) { return (e < E_HALF) ? e + E_HALF : e - E_HALF; }

// ---------------- node norms (pass-1 only; pass-2 norm fused into agg1) ----------------
template<int D>
__global__ __launch_bounds__(256) void row_norm_k(const float* __restrict__ x, float* __restrict__ nrm) {
    int w = (blockIdx.x * 256 + threadIdx.x) >> 6;
    int lane = threadIdx.x & 63;
    if (w >= N_NODES) return;
    const float* row = x + (size_t)w * D;
    float s = 0.f;
#pragma unroll
    for (int i = 0; i < D / 64; ++i) { float v = row[lane + 64 * i]; s = fmaf(v, v, s); }
#pragma unroll
    for (int off = 32; off; off >>= 1) s += __shfl_xor(s, off);
    if (lane == 0) nrm[w] = sqrtf(s);
}

// ------- cosine sim on edge pairs: L lanes/pair, each lane owns one 64B line (16 floats) -------
template<int D, int L, bool MASKED>
__global__ __launch_bounds__(256) void sim_k(const float* __restrict__ f, const float* __restrict__ nrm,
                                             const int* __restrict__ src, const int* __restrict__ dst,
                                             const float* __restrict__ we_mask,
                                             float* __restrict__ sim) {
    static_assert(D / L == 16, "each lane covers 16 floats");
    int g = blockIdx.x * 256 + threadIdx.x;
    int ep = g / L, sl = g % L;
    if (ep >= E_HALF) return;
    bool m0 = true, m1 = true;
    if (MASKED) {
        m0 = we_mask[ep] > 0.f;
        m1 = we_mask[ep + E_HALF] > 0.f;
        if (!m0 && !m1) {               // both directions dropped in pass 1: skip the row gathers
            if (sl == 0) { sim[ep] = 0.f; sim[ep + E_HALF] = 0.f; }
            return;
        }
    }
    int s = src[ep], d = dst[ep];
    const float* fa = f + (size_t)s * D + sl * 16;
    const float* fb = f + (size_t)d * D + sl * 16;
    float acc = 0.f;
#pragma unroll
    for (int i = 0; i < 16; i += 4) {
        float4 va = *(const float4*)(fa + i);
        float4 vb = *(const float4*)(fb + i);
        acc = fmaf(va.x, vb.x, acc); acc = fmaf(va.y, vb.y, acc);
        acc = fmaf(va.z, vb.z, acc); acc = fmaf(va.w, vb.w, acc);
    }
#pragma unroll
    for (int off = L / 2; off; off >>= 1) acc += __shfl_xor(acc, off);
    if (sl == 0) {
        float na = nrm[s]; na = (na == 0.f) ? 1.f : na;
        float nb = nrm[d]; nb = (nb == 0.f) ? 1.f : nb;
        float c = acc / (na * nb);
        float t = (c < 0.1f) ? 0.f : c;      // t >= 0 always
        sim[ep]          = m0 ? t : 0.f;
        sim[ep + E_HALF] = m1 ? t : 0.f;
    }
}

// ---------------- rowsum[j] = sum of sim over out-edges (CSR row j), 4 lanes/node ----------------
__global__ __launch_bounds__(256) void rowsum_k(const float* __restrict__ sim, const int* __restrict__ row_start,
                                                const int2* __restrict__ csr, float* __restrict__ rowsum) {
    int g = blockIdx.x * 256 + threadIdx.x;
    int j = g >> 2, l = g & 3;
    if (j >= N_NODES) return;
    int e0 = row_start[j], e1 = row_start[j + 1];
    float s = 0.f;
    for (int t = e0 + l; t < e1; t += 4) s += sim[csr[t].y];
    s += __shfl_xor(s, 1); s += __shfl_xor(s, 2);
    if (l == 0) rowsum[j] = s;
}

// ---------------- fused L1-normalize + learnable keep/drop -> w_e (pure streaming) ----------------
__global__ __launch_bounds__(256) void keep_k(const float* __restrict__ sim,
                                              const int* __restrict__ src, const int* __restrict__ dst,
                                              const float* __restrict__ rowsum,
                                              const float* __restrict__ Wd, const float* __restrict__ bd,
                                              float* __restrict__ we) {
    int e = blockIdx.x * 256 + threadIdx.x;
    if (e >= E_TOT) return;
    int s = src[e], d = dst[e];
    float rs = rowsum[s]; rs = (rs == 0.f) ? 1.f : rs;
    float rd = rowsum[d]; rd = (rd == 0.f) ? 1.f : rd;      // src[rev[e]] == dst[e]
    float ae = sim[e] / rs;
    float ar = sim[REV(e)] / rd;
    float z = ae * Wd[0] + ar * Wd[1] + bd[0];
    float av = (z > 0.f) ? ae : 0.f;          // sigmoid(z)>0.5 <=> z>0
    we[e] = (av > 0.f) ? expf(av) : 0.f;
}

// ------- per-node: deg, degc -> w_s, dis; ALSO emits slot-ordered wrev[t] = we[REV(eid)] -------
__global__ __launch_bounds__(256) void nodeB_k(const float* __restrict__ we, const int* __restrict__ row_start,
                                               const int2* __restrict__ csr,
                                               float* __restrict__ w_s, float* __restrict__ dis,
                                               float* __restrict__ wrev) {
    int g = blockIdx.x * 256 + threadIdx.x;
    int j = g >> 2, l = g & 3;
    if (j >= N_NODES) return;
    int e0 = row_start[j], e1 = row_start[j + 1];
    float c = 0.f, s = 0.f;
    for (int t = e0 + l; t < e1; t += 4) {
        int eid = csr[t].y;
        float wr = we[REV(eid)];            // surviving in-edge weight
        wrev[t] = wr;                       // slot-ordered for the agg loops
        c += (we[eid] > 0.f) ? 1.f : 0.f;   // deg: surviving out-edges
        s += wr;                            // degc
    }
    c += __shfl_xor(c, 1); c += __shfl_xor(c, 2);
    s += __shfl_xor(s, 1); s += __shfl_xor(s, 2);
    if (l == 0) {
        float ws = expf(1.f / (c + 1.f));
        w_s[j] = ws;
        dis[j] = 1.f / sqrtf(s + ws + 1.f);
    }
}

// ======== two-phase binned CSR build (write-locality by construction) ========
// Phase A: append edge to (sub=blockIdx&7, bucket=src>>7) stream. Same-stream
// appends are consecutive addresses written by one XCD class -> lines assemble in L2.
// Payload: [eid:20 | src&127:7 | dst:17] in one 8B word.
__global__ __launch_bounds__(256) void fillA_k(const int* __restrict__ src, const int* __restrict__ dst,
                                               int* __restrict__ bcur, long long* __restrict__ stage) {
    int e = blockIdx.x * 256 + threadIdx.x;
    if (e >= E_TOT) return;
    int s = src[e];
    int buk = s >> 7;
    int sub = blockIdx.x & 7;
    int p = atomicAdd(&bcur[sub * NBUK + buk], 1);
    if (p < CAP) {
        long long pk = ((long long)e << 24) | ((long long)(s & 127) << 17) | (unsigned)dst[e];
        stage[((size_t)(sub * NBUK + buk)) * CAP + p] = pk;
    }
}

// exclusive scan of per-bucket totals -> bucket bases (1 block; replaces count+scan1/2/3)
__global__ __launch_bounds__(256) void bukscan_k(const int* __restrict__ bcur, int* __restrict__ bbase) {
    __shared__ int part[256];
    int t = threadIdx.x;
    int loc[4]; int s = 0;
#pragma unroll
    for (int i = 0; i < 4; ++i) {
        int b = t * 4 + i; int c = 0;
        if (b < NBUK)
#pragma unroll
            for (int sub = 0; sub < NSUB; ++sub) c += min(bcur[sub * NBUK + b], CAP);
        loc[i] = c; s += c;
    }
    part[t] = s;
    __syncthreads();
    if (t == 0) { int run = 0; for (int k = 0; k < 256; ++k) { int v = part[k]; part[k] = run; run += v; } }
    __syncthreads();
    int base = part[t];
#pragma unroll
    for (int i = 0; i < 4; ++i) {
        int b = t * 4 + i;
        if (b < NBUK) { bbase[b] = base; base += loc[i]; }
    }
}

// Phase B: one block per bucket. LDS histogram -> row_start for its 128 nodes,
// then place edges into the bucket's contiguous csr region (~10KB, one block/XCD).
__global__ __launch_bounds__(256) void fillB_k(const long long* __restrict__ stage, const int* __restrict__ bcur,
                                               const int* __restrict__ bbase,
                                               int* __restrict__ row_start, int2* __restrict__ csr) {
    int buk = blockIdx.x;
    int n0 = buk << 7;
    __shared__ int lcnt[128], lofs[129], lcur[128];
    int t = threadIdx.x;
    if (t < 128) { lcnt[t] = 0; lcur[t] = 0; }
    __syncthreads();
    int cnts[NSUB];
#pragma unroll
    for (int sub = 0; sub < NSUB; ++sub) {
        int n = min(bcur[sub * NBUK + buk], CAP);
        cnts[sub] = n;
        const long long* sp = stage + ((size_t)(sub * NBUK + buk)) * CAP;
        for (int k = t; k < n; k += 256)
            atomicAdd(&lcnt[(int)((sp[k] >> 17) & 127)], 1);
    }
    __syncthreads();
    if (t == 0) { int run = 0; for (int i = 0; i < 128; ++i) { lofs[i] = run; run += lcnt[i]; } lofs[128] = run; }
    __syncthreads();
    int base = bbase[buk];
    if (t < 128 && n0 + t < N_NODES) row_start[n0 + t] = base + lofs[t];
    if (buk == NBUK - 1 && t == 0)   row_start[N_NODES] = base + lofs[128];
#pragma unroll
    for (int sub = 0; sub < NSUB; ++sub) {
        int n = cnts[sub];
        const long long* sp = stage + ((size_t)(sub * NBUK + buk)) * CAP;
        for (int k = t; k < n; k += 256) {
            long long pk = sp[k];
            int d17 = (int)(pk & 0x1FFFF);
            int slo = (int)((pk >> 17) & 127);
            int eid = (int)(pk >> 24);
            int r = atomicAdd(&lcur[slo], 1);
            csr[base + lofs[slo] + r] = make_int2(d17, eid);
        }
    }
}

// ---------------- GEMM1: hs = (x[N,128] @ W1[128,64]) * dis[row] ----------------
__global__ __launch_bounds__(256) void gemm1_k(const float* __restrict__ X, const float* __restrict__ W,
                                               const float* __restrict__ dis, float* __restrict__ Y) {
    __shared__ float sXT[8][128];
    __shared__ float sW[8][64];
    int tid = threadIdx.x;
    int row0 = blockIdx.x * 128;
    int tc = tid & 15;
    int tr = tid >> 4;
    float acc[8][4] = {};
    int lrow = tid >> 1, lhalf = tid & 1;
    int grow = row0 + lrow;
    for (int k0 = 0; k0 < NFEAT; k0 += 8) {
        float4 v = make_float4(0.f, 0.f, 0.f, 0.f);
        if (grow < N_NODES) v = *(const float4*)(X + (size_t)grow * NFEAT + k0 + lhalf * 4);
        sXT[lhalf * 4 + 0][lrow] = v.x;
        sXT[lhalf * 4 + 1][lrow] = v.y;
        sXT[lhalf * 4 + 2][lrow] = v.z;
        sXT[lhalf * 4 + 3][lrow] = v.w;
        float2 wv2 = *(const float2*)(W + (size_t)(k0 + (tid >> 5)) * NHID + (tid & 31) * 2);
        *(float2*)&sW[tid >> 5][(tid & 31) * 2] = wv2;
        __syncthreads();
#pragma unroll
        for (int k = 0; k < 8; ++k) {
            float4 xa = *(const float4*)&sXT[k][tr * 8];
            float4 xb = *(const float4*)&sXT[k][tr * 8 + 4];
            float4 wv = *(const float4*)&sW[k][tc * 4];
            float xr[8] = {xa.x, xa.y, xa.z, xa.w, xb.x, xb.y, xb.z, xb.w};
            float wr[4] = {wv.x, wv.y, wv.z, wv.w};
#pragma unroll
            for (int i = 0; i < 8; ++i)
#pragma unroll
                for (int jj = 0; jj < 4; ++jj)
                    acc[i][jj] = fmaf(xr[i], wr[jj], acc[i][jj]);
        }
        __syncthreads();
    }
#pragma unroll
    for (int i = 0; i < 8; ++i) {
        int r = row0 + tr * 8 + i;
        if (r < N_NODES) {
            float dr = dis[r];
            *(float4*)(Y + (size_t)r * NHID + tc * 4) =
                make_float4(acc[i][0] * dr, acc[i][1] * dr, acc[i][2] * dr, acc[i][3] * dr);
        }
    }
}

// ---------------- GEMM2: hs2 = (h[N,64] @ W2[64,40]) * dis[row] ----------------
__global__ __launch_bounds__(256) void gemm2_k(const float* __restrict__ X, const float* __restrict__ W,
                                               const float* __restrict__ dis, float* __restrict__ Y) {
    __shared__ float sXT[8][128];
    __shared__ float sW[320];
    int tid = threadIdx.x;
    int row0 = blockIdx.x * 128;
    int tc = tid & 7;
    int tr = tid >> 3;
    float acc[4][5] = {};
    int lrow = tid >> 1, lhalf = tid & 1;
    int grow = row0 + lrow;
    for (int k0 = 0; k0 < NHID; k0 += 8) {
        float4 v = make_float4(0.f, 0.f, 0.f, 0.f);
        if (grow < N_NODES) v = *(const float4*)(X + (size_t)grow * NHID + k0 + lhalf * 4);
        sXT[lhalf * 4 + 0][lrow] = v.x;
        sXT[lhalf * 4 + 1][lrow] = v.y;
        sXT[lhalf * 4 + 2][lrow] = v.z;
        sXT[lhalf * 4 + 3][lrow] = v.w;
        if (tid < 160) {
            float2 w2 = *(const float2*)(W + k0 * NCLS + tid * 2);
            sW[tid * 2] = w2.x; sW[tid * 2 + 1] = w2.y;
        }
        __syncthreads();
#pragma unroll
        for (int k = 0; k < 8; ++k) {
            float4 xv = *(const float4*)&sXT[k][tr * 4];
            float xr[4] = {xv.x, xv.y, xv.z, xv.w};
            float wr[5];
#pragma unroll
            for (int jj = 0; jj < 5; ++jj) wr[jj] = sW[k * NCLS + tc * 5 + jj];
#pragma unroll
            for (int i = 0; i < 4; ++i)
#pragma unroll
                for (int jj = 0; jj < 5; ++jj)
                    acc[i][jj] = fmaf(xr[i], wr[jj], acc[i][jj]);
        }
        __syncthreads();
    }
#pragma unroll
    for (int i = 0; i < 4; ++i) {
        int r = row0 + tr * 4 + i;
        if (r < N_NODES) {
            float dr = dis[r];
#pragma unroll
            for (int jj = 0; jj < 5; ++jj) Y[(size_t)r * NCLS + tc * 5 + jj] = acc[i][jj] * dr;
        }
    }
}

// -------- aggregation layer 1 on dis-scaled hs: acc=SUM wrev*hs[col]+(w_s+1)*hs[j]; out=acc*dis[j]+b --------
__global__ __launch_bounds__(256) void agg1_k(const float* __restrict__ hs, const int* __restrict__ row_start,
                                              const int2* __restrict__ csr, const float* __restrict__ wrev,
                                              const float* __restrict__ dis, const float* __restrict__ w_s,
                                              const float* __restrict__ b, float* __restrict__ h,
                                              float* __restrict__ nrm) {
    int j = (blockIdx.x * 256 + threadIdx.x) >> 6;
    int lane = threadIdx.x & 63;
    if (j >= N_NODES) return;
    int e0 = row_start[j], e1 = row_start[j + 1];
    float acc = 0.f;
    int t = e0;
    for (; t + 4 <= e1; t += 4) {
        int2 c0 = csr[t], c1 = csr[t + 1], c2 = csr[t + 2], c3 = csr[t + 3];
        float w0 = wrev[t], w1 = wrev[t + 1], w2 = wrev[t + 2], w3 = wrev[t + 3];
        float v0 = hs[(size_t)c0.x * NHID + lane];
        float v1 = hs[(size_t)c1.x * NHID + lane];
        float v2 = hs[(size_t)c2.x * NHID + lane];
        float v3 = hs[(size_t)c3.x * NHID + lane];
        acc = fmaf(w0, v0, acc); acc = fmaf(w1, v1, acc);
        acc = fmaf(w2, v2, acc); acc = fmaf(w3, v3, acc);
    }
    for (; t < e1; ++t)
        acc = fmaf(wrev[t], hs[(size_t)csr[t].x * NHID + lane], acc);
    acc = fmaf(w_s[j] + 1.f, hs[(size_t)j * NHID + lane], acc);
    float v = fmaxf(fmaf(acc, dis[j], b[lane]), 0.f);
    h[(size_t)j * NHID + lane] = v;
    float s = v * v;                         // fused row_norm for pass 2
#pragma unroll
    for (int off = 32; off; off >>= 1) s += __shfl_xor(s, off);
    if (lane == 0) nrm[j] = sqrtf(s);
}

// -------- aggregation layer 2 + log_softmax on dis-scaled hs2 --------
__global__ __launch_bounds__(256) void agg2_k(const float* __restrict__ hs2, const int* __restrict__ row_start,
                                              const int2* __restrict__ csr, const float* __restrict__ wrev,
                                              const float* __restrict__ dis, const float* __restrict__ w_s,
                                              const float* __restrict__ b, float* __restrict__ out) {
    int j = (blockIdx.x * 256 + threadIdx.x) >> 6;
    int lane = threadIdx.x & 63;
    if (j >= N_NODES) return;
    int lc = (lane < NCLS) ? lane : (NCLS - 1);   // clamped gather lane (same cachelines)
    int e0 = row_start[j], e1 = row_start[j + 1];
    float acc = 0.f;
    int t = e0;
    for (; t + 4 <= e1; t += 4) {
        int2 c0 = csr[t], c1 = csr[t + 1], c2 = csr[t + 2], c3 = csr[t + 3];
        float w0 = wrev[t], w1 = wrev[t + 1], w2 = wrev[t + 2], w3 = wrev[t + 3];
        float v0 = hs2[(size_t)c0.x * NCLS + lc];
        float v1 = hs2[(size_t)c1.x * NCLS + lc];
        float v2 = hs2[(size_t)c2.x * NCLS + lc];
        float v3 = hs2[(size_t)c3.x * NCLS + lc];
        acc = fmaf(w0, v0, acc); acc = fmaf(w1, v1, acc);
        acc = fmaf(w2, v2, acc); acc = fmaf(w3, v3, acc);
    }
    for (; t < e1; ++t)
        acc = fmaf(wrev[t], hs2[(size_t)csr[t].x * NCLS + lc], acc);
    acc = fmaf(w_s[j] + 1.f, hs2[(size_t)j * NCLS + lc], acc);
    float v = (lane < NCLS) ? fmaf(acc, dis[j], b[lane]) : -1e30f;
    float m = v;
#pragma unroll
    for (int off = 32; off; off >>= 1) m = fmaxf(m, __shfl_xor(m, off));
    float ex = (lane < NCLS) ? expf(v - m) : 0.f;
    float ssum = ex;
#pragma unroll
    for (int off = 32; off; off >>= 1) ssum += __shfl_xor(ssum, off);
    if (lane < NCLS) out[(size_t)j * NCLS + lane] = v - m - logf(ssum);
}

extern "C" void kernel_launch(void* const* d_in, const int* in_sizes, int n_in,
                              void* d_out, int out_size, void* d_ws, size_t ws_size,
                              hipStream_t stream) {
    (void)in_sizes; (void)n_in; (void)out_size; (void)ws_size;
    const float* x  = (const float*)d_in[0];
    const int*   src = (const int*)d_in[1];
    const int*   dst = (const int*)d_in[2];
    const float* W1 = (const float*)d_in[4];
    const float* b1 = (const float*)d_in[5];
    const float* W2 = (const float*)d_in[6];
    const float* b2 = (const float*)d_in[7];
    const float* Wd = (const float*)d_in[8];
    const float* bd = (const float*)d_in[9];
    float* out = (float*)d_out;

    char* ws = (char*)d_ws;
    size_t off = 0;
    auto alloc = [&](size_t bytes) -> void* {
        void* p = ws + off;
        off = (off + bytes + 255) & ~(size_t)255;
        return p;
    };
    int*   bcur   = (int*)alloc((size_t)NSUB * NBUK * 4);   // append cursors (zeroed)
    int*   bbase  = (int*)alloc((size_t)NBUK * 4);
    float* nrm    = (float*)alloc((size_t)N_NODES * 4);
    float* rowsum = (float*)alloc((size_t)N_NODES * 4);
    float* w_s    = (float*)alloc((size_t)N_NODES * 4);
    float* dis    = (float*)alloc((size_t)N_NODES * 4);
    float* sbuf   = (float*)alloc((size_t)E_TOT * 4);   // raw masked sim values
    float* we1    = (float*)alloc((size_t)E_TOT * 4);
    float* we2    = (float*)alloc((size_t)E_TOT * 4);
    float* wrev   = (float*)alloc((size_t)E_TOT * 4);   // slot-ordered in-edge weights
    float* hs     = (float*)alloc((size_t)N_NODES * NHID * 4);  // dis-scaled gemm output
    float* h      = (float*)alloc((size_t)N_NODES * NHID * 4);
    int*  row_start = (int*)alloc((size_t)(N_NODES + 1) * 4);
    int2* csr       = (int2*)alloc((size_t)E_TOT * 8);
    // staging aliases hs: 8*782*448*8B = 22.4MB <= 25.6MB, dead before gemm1 writes hs
    long long* stage = (long long*)hs;

    const int BE  = (E_TOT + 255) / 256;
    const int BW  = (N_NODES * 64 + 255) / 256;
    const int BQ  = (N_NODES * 4 + 255) / 256;
    const int BS8 = (E_HALF * 8 + 255) / 256;
    const int BS4 = (E_HALF * 4 + 255) / 256;
    const int BG  = (N_NODES + 127) / 128;

    // CSR by src (topology shared by both layers; symmetric graph)
    hipMemsetAsync(bcur, 0, (size_t)NSUB * NBUK * 4, stream);
    fillA_k<<<BE, 256, 0, stream>>>(src, dst, bcur, stage);
    bukscan_k<<<1, 256, 0, stream>>>(bcur, bbase);
    fillB_k<<<NBUK, 256, 0, stream>>>(stage, bcur, bbase, row_start, csr);

    // ---- pass 1: attention on raw features ----
    row_norm_k<NFEAT><<<BW, 256, 0, stream>>>(x, nrm);
    sim_k<NFEAT, 8, false><<<BS8, 256, 0, stream>>>(x, nrm, src, dst, nullptr, sbuf);
    rowsum_k<<<BQ, 256, 0, stream>>>(sbuf, row_start, csr, rowsum);
    keep_k<<<BE, 256, 0, stream>>>(sbuf, src, dst, rowsum, Wd, bd, we1);
    nodeB_k<<<BQ, 256, 0, stream>>>(we1, row_start, csr, w_s, dis, wrev);
    gemm1_k<<<BG, 256, 0, stream>>>(x, W1, dis, hs);
    agg1_k<<<BW, 256, 0, stream>>>(hs, row_start, csr, wrev, dis, w_s, b1, h, nrm);

    // ---- pass 2: attention on hidden features ----
    sim_k<NHID, 4, true><<<BS4, 256, 0, stream>>>(h, nrm, src, dst, we1, sbuf);
    rowsum_k<<<BQ, 256, 0, stream>>>(sbuf, row_start, csr, rowsum);
    keep_k<<<BE, 256, 0, stream>>>(sbuf, src, dst, rowsum, Wd, bd, we2);
    nodeB_k<<<BQ, 256, 0, stream>>>(we2, row_start, csr, w_s, dis, wrev);
    gemm2_k<<<BG, 256, 0, stream>>>(h, W2, dis, hs);      // hs reused as [N,40]
    agg2_k<<<BW, 256, 0, stream>>>(hs, row_start, csr, wrev, dis, w_s, b2, out);
}

// Round 9
// 495.007 us; speedup vs baseline: 1.4188x; 1.0996x over previous
//
#include <hip/hip_runtime.h>

#define N_NODES 100000
#define E_HALF  500000
#define E_TOT   1000000
#define NFEAT   128
#define NHID    64
#define NCLS    40
#define NBUK    782            // ceil(N_NODES/128): 128-node buckets
#define NSUB    8              // sub-streams per bucket (blockIdx&7 ~ XCD class)
#define CAP     448            // slots per (sub,bucket) stream; mean 160, +22 sigma

// rev is arithmetic by construction: rev = concat(arange+E_HALF, arange)
__device__ __forceinline__ int REV(int e) { return (e < E_HALF) ? e + E_HALF : e - E_HALF; }
__device__ __forceinline__ float guard0(float v) { return (v == 0.f) ? 1.f : v; }

// ---- pass-1 cosine sim on pairs: inline norms, pair-indexed output (both dirs equal pre-mask) ----
template<int D, int L>
__global__ __launch_bounds__(256) void sim1_k(const float* __restrict__ f,
                                              const int* __restrict__ src, const int* __restrict__ dst,
                                              float* __restrict__ spair) {
    static_assert(D / L == 16, "each lane covers 16 floats (one 64B line)");
    int g = blockIdx.x * 256 + threadIdx.x;
    int ep = g / L, sl = g % L;
    if (ep >= E_HALF) return;
    int s = src[ep], d = dst[ep];
    const float* fa = f + (size_t)s * D + sl * 16;
    const float* fb = f + (size_t)d * D + sl * 16;
    float dot = 0.f, na2 = 0.f, nb2 = 0.f;
#pragma unroll
    for (int i = 0; i < 16; i += 4) {
        float4 va = *(const float4*)(fa + i);
        float4 vb = *(const float4*)(fb + i);
        dot = fmaf(va.x, vb.x, dot); dot = fmaf(va.y, vb.y, dot);
        dot = fmaf(va.z, vb.z, dot); dot = fmaf(va.w, vb.w, dot);
        na2 = fmaf(va.x, va.x, na2); na2 = fmaf(va.y, va.y, na2);
        na2 = fmaf(va.z, va.z, na2); na2 = fmaf(va.w, va.w, na2);
        nb2 = fmaf(vb.x, vb.x, nb2); nb2 = fmaf(vb.y, vb.y, nb2);
        nb2 = fmaf(vb.z, vb.z, nb2); nb2 = fmaf(vb.w, vb.w, nb2);
    }
#pragma unroll
    for (int off = L / 2; off; off >>= 1) {
        dot += __shfl_xor(dot, off);
        na2 += __shfl_xor(na2, off);
        nb2 += __shfl_xor(nb2, off);
    }
    if (sl == 0) {
        float na = guard0(sqrtf(na2));
        float nb = guard0(sqrtf(nb2));
        float c = dot / (na * nb);
        spair[ep] = (c < 0.1f) ? 0.f : c;
    }
}

// ---- pass-2 sim: mask gate recomputed from pass-1 spair/rowsum; inline norms of h ----
template<int D, int L>
__global__ __launch_bounds__(256) void sim2_k(const float* __restrict__ f,
                                              const int* __restrict__ src, const int* __restrict__ dst,
                                              const float* __restrict__ spair1, const float* __restrict__ rs1,
                                              const float* __restrict__ Wd, const float* __restrict__ bd,
                                              float* __restrict__ sim) {
    static_assert(D / L == 16, "each lane covers 16 floats (one 64B line)");
    int g = blockIdx.x * 256 + threadIdx.x;
    int ep = g / L, sl = g % L;
    if (ep >= E_HALF) return;
    int s = src[ep], d = dst[ep];
    // recompute the pass-1 keep gates (we1>0  <=>  z>0 && a>0)
    float sp = spair1[ep];
    float rsv = guard0(rs1[s]);
    float rdv = guard0(rs1[d]);
    float ae = sp / rsv, ar = sp / rdv;
    float w0 = Wd[0], w1 = Wd[1], b0 = bd[0];
    bool m0 = (ae * w0 + ar * w1 + b0 > 0.f) && (ae > 0.f);
    bool m1 = (ar * w0 + ae * w1 + b0 > 0.f) && (ar > 0.f);
    if (!m0 && !m1) {               // both directions dropped in pass 1: skip the row gathers
        if (sl == 0) { sim[ep] = 0.f; sim[ep + E_HALF] = 0.f; }
        return;
    }
    const float* fa = f + (size_t)s * D + sl * 16;
    const float* fb = f + (size_t)d * D + sl * 16;
    float dot = 0.f, na2 = 0.f, nb2 = 0.f;
#pragma unroll
    for (int i = 0; i < 16; i += 4) {
        float4 va = *(const float4*)(fa + i);
        float4 vb = *(const float4*)(fb + i);
        dot = fmaf(va.x, vb.x, dot); dot = fmaf(va.y, vb.y, dot);
        dot = fmaf(va.z, vb.z, dot); dot = fmaf(va.w, vb.w, dot);
        na2 = fmaf(va.x, va.x, na2); na2 = fmaf(va.y, va.y, na2);
        na2 = fmaf(va.z, va.z, na2); na2 = fmaf(va.w, va.w, na2);
        nb2 = fmaf(vb.x, vb.x, nb2); nb2 = fmaf(vb.y, vb.y, nb2);
        nb2 = fmaf(vb.z, vb.z, nb2); nb2 = fmaf(vb.w, vb.w, nb2);
    }
#pragma unroll
    for (int off = L / 2; off; off >>= 1) {
        dot += __shfl_xor(dot, off);
        na2 += __shfl_xor(na2, off);
        nb2 += __shfl_xor(nb2, off);
    }
    if (sl == 0) {
        float na = guard0(sqrtf(na2));
        float nb = guard0(sqrtf(nb2));
        float c = dot / (na * nb);
        float t = (c < 0.1f) ? 0.f : c;
        sim[ep]          = m0 ? t : 0.f;
        sim[ep + E_HALF] = m1 ? t : 0.f;
    }
}

// ---- rowsum (pass 1): gather pair-indexed spair (2MB, L2-resident), 4 lanes/node ----
__global__ __launch_bounds__(256) void rowsum1_k(const float* __restrict__ spair, const int* __restrict__ row_start,
                                                 const int2* __restrict__ csr, float* __restrict__ rowsum) {
    int g = blockIdx.x * 256 + threadIdx.x;
    int j = g >> 2, l = g & 3;
    if (j >= N_NODES) return;
    int e0 = row_start[j], e1 = row_start[j + 1];
    float s = 0.f;
    for (int t = e0 + l; t < e1; t += 4) {
        int y = csr[t].y;
        s += spair[(y < E_HALF) ? y : y - E_HALF];
    }
    s += __shfl_xor(s, 1); s += __shfl_xor(s, 2);
    if (l == 0) rowsum[j] = s;
}

// ---- rowsum (pass 2): gather edge-indexed masked sim ----
__global__ __launch_bounds__(256) void rowsum2_k(const float* __restrict__ sim, const int* __restrict__ row_start,
                                                 const int2* __restrict__ csr, float* __restrict__ rowsum) {
    int g = blockIdx.x * 256 + threadIdx.x;
    int j = g >> 2, l = g & 3;
    if (j >= N_NODES) return;
    int e0 = row_start[j], e1 = row_start[j + 1];
    float s = 0.f;
    for (int t = e0 + l; t < e1; t += 4) s += sim[csr[t].y];
    s += __shfl_xor(s, 1); s += __shfl_xor(s, 2);
    if (l == 0) rowsum[j] = s;
}

// ---- nodeB pass 1: fused keep-gate; deg, degc, wrev directly from (spair, rowsum) ----
__global__ __launch_bounds__(256) void nodeB1_k(const float* __restrict__ spair, const int* __restrict__ row_start,
                                                const int2* __restrict__ csr, const float* __restrict__ rs,
                                                const float* __restrict__ Wd, const float* __restrict__ bd,
                                                float* __restrict__ w_s, float* __restrict__ dis,
                                                float* __restrict__ wrev) {
    int g = blockIdx.x * 256 + threadIdx.x;
    int j = g >> 2, l = g & 3;
    if (j >= N_NODES) return;
    int e0 = row_start[j], e1 = row_start[j + 1];
    float rsj = guard0(rs[j]);
    float w0 = Wd[0], w1 = Wd[1], b0 = bd[0];
    float c = 0.f, ssum = 0.f;
    for (int t = e0 + l; t < e1; t += 4) {
        int2 cc = csr[t];
        int y = cc.y;
        float sp = spair[(y < E_HALF) ? y : y - E_HALF];
        float rscol = guard0(rs[cc.x]);
        float ae = sp / rsj;            // a of out-edge (j->col)
        float ar = sp / rscol;          // a of in-edge  (col->j)
        c += ((ae * w0 + ar * w1 + b0 > 0.f) && ae > 0.f) ? 1.f : 0.f;   // deg
        float wr = ((ar * w0 + ae * w1 + b0 > 0.f) && ar > 0.f) ? expf(ar) : 0.f;
        wrev[t] = wr;                   // slot-ordered in-edge weight for agg
        ssum += wr;                     // degc
    }
    c += __shfl_xor(c, 1); c += __shfl_xor(c, 2);
    ssum += __shfl_xor(ssum, 1); ssum += __shfl_xor(ssum, 2);
    if (l == 0) {
        float ws = expf(1.f / (c + 1.f));
        w_s[j] = ws;
        dis[j] = 1.f / sqrtf(ssum + ws + 1.f);
    }
}

// ---- nodeB pass 2: same but per-direction sims (masked zeros already encode pass-1 drops) ----
__global__ __launch_bounds__(256) void nodeB2_k(const float* __restrict__ sim, const int* __restrict__ row_start,
                                                const int2* __restrict__ csr, const float* __restrict__ rs,
                                                const float* __restrict__ Wd, const float* __restrict__ bd,
                                                float* __restrict__ w_s, float* __restrict__ dis,
                                                float* __restrict__ wrev) {
    int g = blockIdx.x * 256 + threadIdx.x;
    int j = g >> 2, l = g & 3;
    if (j >= N_NODES) return;
    int e0 = row_start[j], e1 = row_start[j + 1];
    float rsj = guard0(rs[j]);
    float w0 = Wd[0], w1 = Wd[1], b0 = bd[0];
    float c = 0.f, ssum = 0.f;
    for (int t = e0 + l; t < e1; t += 4) {
        int2 cc = csr[t];
        int y = cc.y;
        float s0 = sim[y];              // out-edge sim
        float s1 = sim[REV(y)];         // in-edge sim
        float rscol = guard0(rs[cc.x]);
        float ae = s0 / rsj;
        float ar = s1 / rscol;
        c += ((ae * w0 + ar * w1 + b0 > 0.f) && ae > 0.f) ? 1.f : 0.f;
        float wr = ((ar * w0 + ae * w1 + b0 > 0.f) && ar > 0.f) ? expf(ar) : 0.f;
        wrev[t] = wr;
        ssum += wr;
    }
    c += __shfl_xor(c, 1); c += __shfl_xor(c, 2);
    ssum += __shfl_xor(ssum, 1); ssum += __shfl_xor(ssum, 2);
    if (l == 0) {
        float ws = expf(1.f / (c + 1.f));
        w_s[j] = ws;
        dis[j] = 1.f / sqrtf(ssum + ws + 1.f);
    }
}

// ======== two-phase binned CSR build (write-locality by construction) ========
__global__ __launch_bounds__(256) void fillA_k(const int* __restrict__ src, const int* __restrict__ dst,
                                               int* __restrict__ bcur, long long* __restrict__ stage) {
    int e = blockIdx.x * 256 + threadIdx.x;
    if (e >= E_TOT) return;
    int s = src[e];
    int buk = s >> 7;
    int sub = blockIdx.x & 7;
    int p = atomicAdd(&bcur[sub * NBUK + buk], 1);
    if (p < CAP) {
        long long pk = ((long long)e << 24) | ((long long)(s & 127) << 17) | (unsigned)dst[e];
        stage[((size_t)(sub * NBUK + buk)) * CAP + p] = pk;
    }
}

__global__ __launch_bounds__(256) void bukscan_k(const int* __restrict__ bcur, int* __restrict__ bbase) {
    __shared__ int part[256];
    int t = threadIdx.x;
    int loc[4]; int s = 0;
#pragma unroll
    for (int i = 0; i < 4; ++i) {
        int b = t * 4 + i; int c = 0;
        if (b < NBUK)
#pragma unroll
            for (int sub = 0; sub < NSUB; ++sub) c += min(bcur[sub * NBUK + b], CAP);
        loc[i] = c; s += c;
    }
    part[t] = s;
    __syncthreads();
    if (t == 0) { int run = 0; for (int k = 0; k < 256; ++k) { int v = part[k]; part[k] = run; run += v; } }
    __syncthreads();
    int base = part[t];
#pragma unroll
    for (int i = 0; i < 4; ++i) {
        int b = t * 4 + i;
        if (b < NBUK) { bbase[b] = base; base += loc[i]; }
    }
}

__global__ __launch_bounds__(256) void fillB_k(const long long* __restrict__ stage, const int* __restrict__ bcur,
                                               const int* __restrict__ bbase,
                                               int* __restrict__ row_start, int2* __restrict__ csr) {
    int buk = blockIdx.x;
    int n0 = buk << 7;
    __shared__ int lcnt[128], lofs[129], lcur[128];
    int t = threadIdx.x;
    if (t < 128) { lcnt[t] = 0; lcur[t] = 0; }
    __syncthreads();
    int cnts[NSUB];
#pragma unroll
    for (int sub = 0; sub < NSUB; ++sub) {
        int n = min(bcur[sub * NBUK + buk], CAP);
        cnts[sub] = n;
        const long long* sp = stage + ((size_t)(sub * NBUK + buk)) * CAP;
        for (int k = t; k < n; k += 256)
            atomicAdd(&lcnt[(int)((sp[k] >> 17) & 127)], 1);
    }
    __syncthreads();
    if (t == 0) { int run = 0; for (int i = 0; i < 128; ++i) { lofs[i] = run; run += lcnt[i]; } lofs[128] = run; }
    __syncthreads();
    int base = bbase[buk];
    if (t < 128 && n0 + t < N_NODES) row_start[n0 + t] = base + lofs[t];
    if (buk == NBUK - 1 && t == 0)   row_start[N_NODES] = base + lofs[128];
#pragma unroll
    for (int sub = 0; sub < NSUB; ++sub) {
        int n = cnts[sub];
        const long long* sp = stage + ((size_t)(sub * NBUK + buk)) * CAP;
        for (int k = t; k < n; k += 256) {
            long long pk = sp[k];
            int d17 = (int)(pk & 0x1FFFF);
            int slo = (int)((pk >> 17) & 127);
            int eid = (int)(pk >> 24);
            int r = atomicAdd(&lcur[slo], 1);
            csr[base + lofs[slo] + r] = make_int2(d17, eid);
        }
    }
}

// ---------------- GEMM1: hs = (x[N,128] @ W1[128,64]) * dis[row] ----------------
__global__ __launch_bounds__(256) void gemm1_k(const float* __restrict__ X, const float* __restrict__ W,
                                               const float* __restrict__ dis, float* __restrict__ Y) {
    __shared__ float sXT[8][128];
    __shared__ float sW[8][64];
    int tid = threadIdx.x;
    int row0 = blockIdx.x * 128;
    int tc = tid & 15;
    int tr = tid >> 4;
    float acc[8][4] = {};
    int lrow = tid >> 1, lhalf = tid & 1;
    int grow = row0 + lrow;
    for (int k0 = 0; k0 < NFEAT; k0 += 8) {
        float4 v = make_float4(0.f, 0.f, 0.f, 0.f);
        if (grow < N_NODES) v = *(const float4*)(X + (size_t)grow * NFEAT + k0 + lhalf * 4);
        sXT[lhalf * 4 + 0][lrow] = v.x;
        sXT[lhalf * 4 + 1][lrow] = v.y;
        sXT[lhalf * 4 + 2][lrow] = v.z;
        sXT[lhalf * 4 + 3][lrow] = v.w;
        float2 wv2 = *(const float2*)(W + (size_t)(k0 + (tid >> 5)) * NHID + (tid & 31) * 2);
        *(float2*)&sW[tid >> 5][(tid & 31) * 2] = wv2;
        __syncthreads();
#pragma unroll
        for (int k = 0; k < 8; ++k) {
            float4 xa = *(const float4*)&sXT[k][tr * 8];
            float4 xb = *(const float4*)&sXT[k][tr * 8 + 4];
            float4 wv = *(const float4*)&sW[k][tc * 4];
            float xr[8] = {xa.x, xa.y, xa.z, xa.w, xb.x, xb.y, xb.z, xb.w};
            float wr[4] = {wv.x, wv.y, wv.z, wv.w};
#pragma unroll
            for (int i = 0; i < 8; ++i)
#pragma unroll
                for (int jj = 0; jj < 4; ++jj)
                    acc[i][jj] = fmaf(xr[i], wr[jj], acc[i][jj]);
        }
        __syncthreads();
    }
#pragma unroll
    for (int i = 0; i < 8; ++i) {
        int r = row0 + tr * 8 + i;
        if (r < N_NODES) {
            float dr = dis[r];
            *(float4*)(Y + (size_t)r * NHID + tc * 4) =
                make_float4(acc[i][0] * dr, acc[i][1] * dr, acc[i][2] * dr, acc[i][3] * dr);
        }
    }
}

// ---------------- GEMM2: hs2 = (h[N,64] @ W2[64,40]) * dis[row] ----------------
__global__ __launch_bounds__(256) void gemm2_k(const float* __restrict__ X, const float* __restrict__ W,
                                               const float* __restrict__ dis, float* __restrict__ Y) {
    __shared__ float sXT[8][128];
    __shared__ float sW[320];
    int tid = threadIdx.x;
    int row0 = blockIdx.x * 128;
    int tc = tid & 7;
    int tr = tid >> 3;
    float acc[4][5] = {};
    int lrow = tid >> 1, lhalf = tid & 1;
    int grow = row0 + lrow;
    for (int k0 = 0; k0 < NHID; k0 += 8) {
        float4 v = make_float4(0.f, 0.f, 0.f, 0.f);
        if (grow < N_NODES) v = *(const float4*)(X + (size_t)grow * NHID + k0 + lhalf * 4);
        sXT[lhalf * 4 + 0][lrow] = v.x;
        sXT[lhalf * 4 + 1][lrow] = v.y;
        sXT[lhalf * 4 + 2][lrow] = v.z;
        sXT[lhalf * 4 + 3][lrow] = v.w;
        if (tid < 160) {
            float2 w2 = *(const float2*)(W + k0 * NCLS + tid * 2);
            sW[tid * 2] = w2.x; sW[tid * 2 + 1] = w2.y;
        }
        __syncthreads();
#pragma unroll
        for (int k = 0; k < 8; ++k) {
            float4 xv = *(const float4*)&sXT[k][tr * 4];
            float xr[4] = {xv.x, xv.y, xv.z, xv.w};
            float wr[5];
#pragma unroll
            for (int jj = 0; jj < 5; ++jj) wr[jj] = sW[k * NCLS + tc * 5 + jj];
#pragma unroll
            for (int i = 0; i < 4; ++i)
#pragma unroll
                for (int jj = 0; jj < 5; ++jj)
                    acc[i][jj] = fmaf(xr[i], wr[jj], acc[i][jj]);
        }
        __syncthreads();
    }
#pragma unroll
    for (int i = 0; i < 4; ++i) {
        int r = row0 + tr * 4 + i;
        if (r < N_NODES) {
            float dr = dis[r];
#pragma unroll
            for (int jj = 0; jj < 5; ++jj) Y[(size_t)r * NCLS + tc * 5 + jj] = acc[i][jj] * dr;
        }
    }
}

// -------- aggregation layer 1 on dis-scaled hs (relu epilogue) --------
__global__ __launch_bounds__(256) void agg1_k(const float* __restrict__ hs, const int* __restrict__ row_start,
                                              const int2* __restrict__ csr, const float* __restrict__ wrev,
                                              const float* __restrict__ dis, const float* __restrict__ w_s,
                                              const float* __restrict__ b, float* __restrict__ h) {
    int j = (blockIdx.x * 256 + threadIdx.x) >> 6;
    int lane = threadIdx.x & 63;
    if (j >= N_NODES) return;
    int e0 = row_start[j], e1 = row_start[j + 1];
    float acc = 0.f;
    int t = e0;
    for (; t + 4 <= e1; t += 4) {
        int2 c0 = csr[t], c1 = csr[t + 1], c2 = csr[t + 2], c3 = csr[t + 3];
        float w0 = wrev[t], w1 = wrev[t + 1], w2 = wrev[t + 2], w3 = wrev[t + 3];
        float v0 = hs[(size_t)c0.x * NHID + lane];
        float v1 = hs[(size_t)c1.x * NHID + lane];
        float v2 = hs[(size_t)c2.x * NHID + lane];
        float v3 = hs[(size_t)c3.x * NHID + lane];
        acc = fmaf(w0, v0, acc); acc = fmaf(w1, v1, acc);
        acc = fmaf(w2, v2, acc); acc = fmaf(w3, v3, acc);
    }
    for (; t < e1; ++t)
        acc = fmaf(wrev[t], hs[(size_t)csr[t].x * NHID + lane], acc);
    acc = fmaf(w_s[j] + 1.f, hs[(size_t)j * NHID + lane], acc);
    h[(size_t)j * NHID + lane] = fmaxf(fmaf(acc, dis[j], b[lane]), 0.f);
}

// -------- aggregation layer 2 + log_softmax on dis-scaled hs2 --------
__global__ __launch_bounds__(256) void agg2_k(const float* __restrict__ hs2, const int* __restrict__ row_start,
                                              const int2* __restrict__ csr, const float* __restrict__ wrev,
                                              const float* __restrict__ dis, const float* __restrict__ w_s,
                                              const float* __restrict__ b, float* __restrict__ out) {
    int j = (blockIdx.x * 256 + threadIdx.x) >> 6;
    int lane = threadIdx.x & 63;
    if (j >= N_NODES) return;
    int lc = (lane < NCLS) ? lane : (NCLS - 1);   // clamped gather lane (same cachelines)
    int e0 = row_start[j], e1 = row_start[j + 1];
    float acc = 0.f;
    int t = e0;
    for (; t + 4 <= e1; t += 4) {
        int2 c0 = csr[t], c1 = csr[t + 1], c2 = csr[t + 2], c3 = csr[t + 3];
        float w0 = wrev[t], w1 = wrev[t + 1], w2 = wrev[t + 2], w3 = wrev[t + 3];
        float v0 = hs2[(size_t)c0.x * NCLS + lc];
        float v1 = hs2[(size_t)c1.x * NCLS + lc];
        float v2 = hs2[(size_t)c2.x * NCLS + lc];
        float v3 = hs2[(size_t)c3.x * NCLS + lc];
        acc = fmaf(w0, v0, acc); acc = fmaf(w1, v1, acc);
        acc = fmaf(w2, v2, acc); acc = fmaf(w3, v3, acc);
    }
    for (; t < e1; ++t)
        acc = fmaf(wrev[t], hs2[(size_t)csr[t].x * NCLS + lc], acc);
    acc = fmaf(w_s[j] + 1.f, hs2[(size_t)j * NCLS + lc], acc);
    float v = (lane < NCLS) ? fmaf(acc, dis[j], b[lane]) : -1e30f;
    float m = v;
#pragma unroll
    for (int off = 32; off; off >>= 1) m = fmaxf(m, __shfl_xor(m, off));
    float ex = (lane < NCLS) ? expf(v - m) : 0.f;
    float ssum = ex;
#pragma unroll
    for (int off = 32; off; off >>= 1) ssum += __shfl_xor(ssum, off);
    if (lane < NCLS) out[(size_t)j * NCLS + lane] = v - m - logf(ssum);
}

extern "C" void kernel_launch(void* const* d_in, const int* in_sizes, int n_in,
                              void* d_out, int out_size, void* d_ws, size_t ws_size,
                              hipStream_t stream) {
    (void)in_sizes; (void)n_in; (void)out_size; (void)ws_size;
    const float* x  = (const float*)d_in[0];
    const int*   src = (const int*)d_in[1];
    const int*   dst = (const int*)d_in[2];
    const float* W1 = (const float*)d_in[4];
    const float* b1 = (const float*)d_in[5];
    const float* W2 = (const float*)d_in[6];
    const float* b2 = (const float*)d_in[7];
    const float* Wd = (const float*)d_in[8];
    const float* bd = (const float*)d_in[9];
    float* out = (float*)d_out;

    char* ws = (char*)d_ws;
    size_t off = 0;
    auto alloc = [&](size_t bytes) -> void* {
        void* p = ws + off;
        off = (off + bytes + 255) & ~(size_t)255;
        return p;
    };
    int*   bcur   = (int*)alloc((size_t)NSUB * NBUK * 4);   // append cursors (zeroed)
    int*   bbase  = (int*)alloc((size_t)NBUK * 4);
    float* rs1    = (float*)alloc((size_t)N_NODES * 4);     // pass-1 rowsum (kept for sim2 gate)
    float* rs2    = (float*)alloc((size_t)N_NODES * 4);
    float* w_s    = (float*)alloc((size_t)N_NODES * 4);
    float* dis    = (float*)alloc((size_t)N_NODES * 4);
    float* spair  = (float*)alloc((size_t)E_HALF * 4);      // pass-1 sim, pair-indexed (2MB)
    float* sbuf2  = (float*)alloc((size_t)E_TOT * 4);       // pass-2 masked sim, edge-indexed
    float* wrev   = (float*)alloc((size_t)E_TOT * 4);       // slot-ordered in-edge weights
    float* hs     = (float*)alloc((size_t)N_NODES * NHID * 4);  // dis-scaled gemm output
    float* h      = (float*)alloc((size_t)N_NODES * NHID * 4);
    int*  row_start = (int*)alloc((size_t)(N_NODES + 1) * 4);
    int2* csr       = (int2*)alloc((size_t)E_TOT * 8);
    // staging aliases hs: 8*782*448*8B = 22.4MB <= 25.6MB, dead before gemm1 writes hs
    long long* stage = (long long*)hs;

    const int BW  = (N_NODES * 64 + 255) / 256;
    const int BQ  = (N_NODES * 4 + 255) / 256;
    const int BE  = (E_TOT + 255) / 256;
    const int BS8 = (E_HALF * 8 + 255) / 256;
    const int BS4 = (E_HALF * 4 + 255) / 256;
    const int BG  = (N_NODES + 127) / 128;

    // CSR by src (topology shared by both layers; symmetric graph)
    hipMemsetAsync(bcur, 0, (size_t)NSUB * NBUK * 4, stream);
    fillA_k<<<BE, 256, 0, stream>>>(src, dst, bcur, stage);
    bukscan_k<<<1, 256, 0, stream>>>(bcur, bbase);
    fillB_k<<<NBUK, 256, 0, stream>>>(stage, bcur, bbase, row_start, csr);

    // ---- pass 1: attention on raw features ----
    sim1_k<NFEAT, 8><<<BS8, 256, 0, stream>>>(x, src, dst, spair);
    rowsum1_k<<<BQ, 256, 0, stream>>>(spair, row_start, csr, rs1);
    nodeB1_k<<<BQ, 256, 0, stream>>>(spair, row_start, csr, rs1, Wd, bd, w_s, dis, wrev);
    gemm1_k<<<BG, 256, 0, stream>>>(x, W1, dis, hs);
    agg1_k<<<BW, 256, 0, stream>>>(hs, row_start, csr, wrev, dis, w_s, b1, h);

    // ---- pass 2: attention on hidden features ----
    sim2_k<NHID, 4><<<BS4, 256, 0, stream>>>(h, src, dst, spair, rs1, Wd, bd, sbuf2);
    rowsum2_k<<<BQ, 256, 0, stream>>>(sbuf2, row_start, csr, rs2);
    nodeB2_k<<<BQ, 256, 0, stream>>>(sbuf2, row_start, csr, rs2, Wd, bd, w_s, dis, wrev);
    gemm2_k<<<BG, 256, 0, stream>>>(h, W2, dis, hs);      // hs reused as [N,40]
    agg2_k<<<BW, 256, 0, stream>>>(hs, row_start, csr, wrev, dis, w_s, b2, out);
}